// Round 5
// baseline (534.794 us; speedup 1.0000x reference)
//
#include <hip/hip_runtime.h>

#define CC   256
#define DHWC 65536          // D*H*W
#define NBC  2              // batch

typedef __attribute__((ext_vector_type(8))) short bf16x8;
typedef __attribute__((ext_vector_type(4))) short bf16x4;
typedef __attribute__((ext_vector_type(4))) float f32x4;

// ---- bf16 split helpers (branchless, bit-level, RTN-even) --------------------
__device__ __forceinline__ short f2bf(float x) {
    unsigned u = __builtin_bit_cast(unsigned, x);
    unsigned r = (u + 0x7fffu + ((u >> 16) & 1u)) >> 16;
    return (short)r;
}
__device__ __forceinline__ float bf2f(short h) {
    unsigned u = ((unsigned)(unsigned short)h) << 16;
    return __builtin_bit_cast(float, u);
}

// swizzled byte offset into a [64 r][64 c] bf16 LDS plane (row stride 128 B).
__device__ __forceinline__ int swz(int r, int c) {
    return (r * 128 + c * 2) ^ ((r & 7) << 4);
}
// richer swizzle for the V^T plane (write pattern is rows at stride 4)
__device__ __forceinline__ int vswz(int r, int c) {
    return (r * 128 + c * 2) ^ (((r ^ (r >> 3)) & 7) << 4);
}
// swizzled byte offset into a [64 s][256 k] bf16 LDS plane (row stride 512 B).
__device__ __forceinline__ int swz512(int s, int k) {
    return (s * 512 + k * 2) ^ ((s & 7) << 4);
}

// ---------------------------------------------------------------------------
// prep: split 5 weight matrices [256][256] fp32 into hi/lo bf16 planes stored
// fragment-major for mfma_f32_16x16x32_bf16 A-operand:
//   frag (fo = o/16, t = k/32): lane l holds W[fo*16 + (l&15)][t*32 + (l>>4)*8 + r]
// matrix m: hi at wsp + m*131072, lo at +65536.
// ---------------------------------------------------------------------------
__global__ void prep_w_kernel(const float* __restrict__ q_w, const float* __restrict__ k_w,
                              const float* __restrict__ v_w, const float* __restrict__ attn_w,
                              const float* __restrict__ out_w, short* __restrict__ wsp)
{
    const int l  = threadIdx.x;          // 64
    const int fo = blockIdx.x;           // 16
    const int t  = blockIdx.y;           // 8
    const int m  = blockIdx.z;           // 5
    const float* w = (m == 0) ? q_w : (m == 1) ? k_w : (m == 2) ? v_w
                   : (m == 3) ? attn_w : out_w;
    short* whi = wsp + (size_t)m * 131072;
    short* wlo = whi + 65536;

    const int o = fo * 16 + (l & 15);
    const int k = t * 32 + (l >> 4) * 8;

    bf16x8 hv, lv;
    #pragma unroll
    for (int r = 0; r < 8; ++r) {
        const float x = w[o * 256 + k + r];
        const short h = f2bf(x);
        hv[r] = h;
        lv[r] = f2bf(x - bf2f(h));
    }
    const int idx = (fo * 8 + t) * 64 + l;
    *(bf16x8*)(whi + idx * 8) = hv;
    *(bf16x8*)(wlo + idx * 8) = lv;
}

// ---------------------------------------------------------------------------
// shared GEMM core: acc += 3-term split MFMA over the full K=256 staged in
// LDS planes hi = lds[swz512], lo = lds + 32768. W frags streamed from L2.
// ---------------------------------------------------------------------------
__device__ __forceinline__ void gemm256(const char* lds, const short* whi,
                                        const short* wlo, int wave, int lane,
                                        f32x4 acc[2][4])
{
    const bf16x8* whf = (const bf16x8*)whi;
    const bf16x8* wlf = (const bf16x8*)wlo;
    #pragma unroll
    for (int t2 = 0; t2 < 8; ++t2) {
        bf16x8 a2h[2], a2l[2];
        #pragma unroll
        for (int f = 0; f < 2; ++f) {
            const int idx = ((wave * 2 + f) * 8 + t2) * 64 + lane;
            a2h[f] = whf[idx];
            a2l[f] = wlf[idx];
        }
        bf16x8 bh[4], bl[4];
        #pragma unroll
        for (int j = 0; j < 4; ++j) {
            const int s = j * 16 + (lane & 15);
            const int k = t2 * 32 + (lane >> 4) * 8;
            const int off = swz512(s, k);
            bh[j] = *(const bf16x8*)(lds + off);
            bl[j] = *(const bf16x8*)(lds + 32768 + off);
        }
        #pragma unroll
        for (int f = 0; f < 2; ++f)
            #pragma unroll
            for (int j = 0; j < 4; ++j) {
                f32x4 c = acc[f][j];
                c = __builtin_amdgcn_mfma_f32_16x16x32_bf16(a2h[f], bh[j], c, 0, 0, 0);
                c = __builtin_amdgcn_mfma_f32_16x16x32_bf16(a2h[f], bl[j], c, 0, 0, 0);
                c = __builtin_amdgcn_mfma_f32_16x16x32_bf16(a2l[f], bh[j], c, 0, 0, 0);
                acc[f][j] = c;
            }
    }
}

// stage a [64 s][256 k] fp32 tile as split-bf16 LDS planes
__device__ __forceinline__ void stage_f32(const float* xb, char* lds, int tid)
{
    const int s_l = tid & 63;
    const int k8  = tid >> 6;
    #pragma unroll
    for (int t = 0; t < 4; ++t) {
        float xr[8];
        #pragma unroll
        for (int r = 0; r < 8; ++r)
            xr[r] = xb[(size_t)(t * 64 + k8 * 8 + r) * DHWC + s_l];
        bf16x8 hv, lv;
        #pragma unroll
        for (int r = 0; r < 8; ++r) {
            const short h = f2bf(xr[r]);
            hv[r] = h;
            lv[r] = f2bf(xr[r] - bf2f(h));
        }
        const int off = swz512(s_l, t * 64 + k8 * 8);
        *(bf16x8*)(lds + off) = hv;
        *(bf16x8*)(lds + 32768 + off) = lv;
    }
}

// stage a [64 s][256 k] packed-u32 (hi|lo bf16) tile into split LDS planes
__device__ __forceinline__ void stage_u32(const unsigned* xb, char* lds, int tid)
{
    const int s_l = tid & 63;
    const int k8  = tid >> 6;
    #pragma unroll
    for (int t = 0; t < 4; ++t) {
        unsigned xu[8];
        #pragma unroll
        for (int r = 0; r < 8; ++r)
            xu[r] = xb[(size_t)(t * 64 + k8 * 8 + r) * DHWC + s_l];
        bf16x8 hv, lv;
        #pragma unroll
        for (int r = 0; r < 8; ++r) {
            hv[r] = (short)(xu[r] & 0xffffu);
            lv[r] = (short)(xu[r] >> 16);
        }
        const int off = swz512(s_l, t * 64 + k8 * 8);
        *(bf16x8*)(lds + off) = hv;
        *(bf16x8*)(lds + 32768 + off) = lv;
    }
}

// ---------------------------------------------------------------------------
// qkv: q = Wq*eeg + qb (packed u32 split-bf16), k = Wk*img + kb (packed u32),
//      v = Wv*img + vb (bf16 hi only, shorts). One img staging feeds K and V.
// ---------------------------------------------------------------------------
__global__ __launch_bounds__(512, 4) void qkv_kernel(
    const float* __restrict__ eeg, const float* __restrict__ img,
    const short* __restrict__ wsp,
    const float* __restrict__ qb, const float* __restrict__ kb,
    const float* __restrict__ vb,
    unsigned* __restrict__ qout, unsigned* __restrict__ kout,
    short* __restrict__ vout)
{
    __shared__ char lds[65536];
    const int tid  = threadIdx.x;
    const int lane = tid & 63;
    const int wave = tid >> 6;
    const size_t boff = (size_t)blockIdx.y * ((size_t)CC * DHWC);
    const int sT = blockIdx.x * 64;
    const int n_l = lane & 15;
    const int m4  = (lane >> 4) * 4;

    f32x4 acc[2][4];

    // ---- phase Q ----
    stage_f32(eeg + boff + sT, lds, tid);
    __syncthreads();
    #pragma unroll
    for (int f = 0; f < 2; ++f)
        #pragma unroll
        for (int j = 0; j < 4; ++j) acc[f][j] = (f32x4){0.f, 0.f, 0.f, 0.f};
    gemm256(lds, wsp, wsp + 65536, wave, lane, acc);
    {
        unsigned* qo = qout + boff + sT;
        #pragma unroll
        for (int f = 0; f < 2; ++f)
            #pragma unroll
            for (int r = 0; r < 4; ++r) {
                const int o = wave * 32 + f * 16 + m4 + r;
                const float bv = qb[o];
                #pragma unroll
                for (int j = 0; j < 4; ++j) {
                    const float val = acc[f][j][r] + bv;
                    const short h = f2bf(val);
                    const short l = f2bf(val - bf2f(h));
                    qo[(size_t)o * DHWC + j * 16 + n_l] =
                        (unsigned)(unsigned short)h | ((unsigned)(unsigned short)l << 16);
                }
            }
    }
    __syncthreads();   // all Q-GEMM LDS reads done

    // ---- phase K/V ----
    stage_f32(img + boff + sT, lds, tid);
    __syncthreads();
    #pragma unroll
    for (int f = 0; f < 2; ++f)
        #pragma unroll
        for (int j = 0; j < 4; ++j) acc[f][j] = (f32x4){0.f, 0.f, 0.f, 0.f};
    gemm256(lds, wsp + 131072, wsp + 131072 + 65536, wave, lane, acc);
    {
        unsigned* ko = kout + boff + sT;
        #pragma unroll
        for (int f = 0; f < 2; ++f)
            #pragma unroll
            for (int r = 0; r < 4; ++r) {
                const int o = wave * 32 + f * 16 + m4 + r;
                const float bv = kb[o];
                #pragma unroll
                for (int j = 0; j < 4; ++j) {
                    const float val = acc[f][j][r] + bv;
                    const short h = f2bf(val);
                    const short l = f2bf(val - bf2f(h));
                    ko[(size_t)o * DHWC + j * 16 + n_l] =
                        (unsigned)(unsigned short)h | ((unsigned)(unsigned short)l << 16);
                }
            }
    }
    #pragma unroll
    for (int f = 0; f < 2; ++f)
        #pragma unroll
        for (int j = 0; j < 4; ++j) acc[f][j] = (f32x4){0.f, 0.f, 0.f, 0.f};
    gemm256(lds, wsp + 2 * 131072, wsp + 2 * 131072 + 65536, wave, lane, acc);
    {
        short* vo = vout + boff + sT;
        #pragma unroll
        for (int f = 0; f < 2; ++f)
            #pragma unroll
            for (int r = 0; r < 4; ++r) {
                const int o = wave * 32 + f * 16 + m4 + r;
                const float bv = vb[o];
                #pragma unroll
                for (int j = 0; j < 4; ++j)
                    vo[(size_t)o * DHWC + j * 16 + n_l] = f2bf(acc[f][j][r] + bv);
            }
    }
}

// ---------------------------------------------------------------------------
// attention. One block (256 thr = 4 waves) per (b,c,d) slab.
// Inputs pre-split: q,k packed u32 (hi|lo), v bf16 shorts.
// Writes wv packed u32 IN-PLACE over the k buffer (same slab bytes, read-
// before-write within the block, slabs disjoint across blocks).
// ---------------------------------------------------------------------------
__global__ __launch_bounds__(256, 4) void attn_mfma_kernel(
    const unsigned* __restrict__ qpk, unsigned* kpk,
    const short* __restrict__ vsh)
{
    __shared__ char lds[40960];
    const int QHI = 0, QLO = 8192, KHI = 16384, KLO = 24576, VT = 32768;

    const int tid  = threadIdx.x;
    const int lane = tid & 63;
    const int wsx  = tid >> 6;           // wave 0..3
    const size_t base = (size_t)blockIdx.x * 4096;

    // ---- stage q, k from packed u32 (unpack only, no conversion) ----
    {
        const unsigned* qpl = qpk + base;
        const unsigned* kpl = kpk + base;
        #pragma unroll
        for (int it = 0; it < 4; ++it) {
            const int e = it * 1024 + tid * 4;
            const int h = e >> 6, w = e & 63;
            const uint4 qu = *(const uint4*)(qpl + e);
            const uint4 ku = *(const uint4*)(kpl + e);
            bf16x4 qh4, ql4, kh4, kl4;
            qh4[0] = (short)qu.x; ql4[0] = (short)(qu.x >> 16);
            qh4[1] = (short)qu.y; ql4[1] = (short)(qu.y >> 16);
            qh4[2] = (short)qu.z; ql4[2] = (short)(qu.z >> 16);
            qh4[3] = (short)qu.w; ql4[3] = (short)(qu.w >> 16);
            kh4[0] = (short)ku.x; kl4[0] = (short)(ku.x >> 16);
            kh4[1] = (short)ku.y; kl4[1] = (short)(ku.y >> 16);
            kh4[2] = (short)ku.z; kl4[2] = (short)(ku.z >> 16);
            kh4[3] = (short)ku.w; kl4[3] = (short)(ku.w >> 16);
            const int off = swz(h, w);
            *(bf16x4*)(lds + QHI + off) = qh4;
            *(bf16x4*)(lds + QLO + off) = ql4;
            *(bf16x4*)(lds + KHI + off) = kh4;
            *(bf16x4*)(lds + KLO + off) = kl4;
        }
        // ---- stage V transposed (shorts, no conversion): vt[w][x] = V[x][w]
        const short* vpl = vsh + base;
        const int x0 = (tid >> 4) * 4;
        const int w0 = (tid & 15) * 4;
        bf16x4 vr[4];
        #pragma unroll
        for (int i = 0; i < 4; ++i)
            vr[i] = *(const bf16x4*)(vpl + (x0 + i) * 64 + w0);
        #pragma unroll
        for (int j = 0; j < 4; ++j) {
            bf16x4 tv;
            #pragma unroll
            for (int i = 0; i < 4; ++i) tv[i] = vr[i][j];
            *(bf16x4*)(lds + VT + vswz(w0 + j, x0)) = tv;
        }
    }
    __syncthreads();

    // ---- QK^T: S[h][x] for h in own strip (3-term split) ----
    f32x4 acc[4];
    #pragma unroll
    for (int j = 0; j < 4; ++j) acc[j] = (f32x4){0.f, 0.f, 0.f, 0.f};

    const int arow = wsx * 16 + (lane & 15);
    #pragma unroll
    for (int kk = 0; kk < 2; ++kk) {
        const int kcol = kk * 32 + (lane >> 4) * 8;
        const bf16x8 aqh = *(const bf16x8*)(lds + QHI + swz(arow, kcol));
        const bf16x8 aql = *(const bf16x8*)(lds + QLO + swz(arow, kcol));
        #pragma unroll
        for (int j = 0; j < 4; ++j) {
            const int brow = j * 16 + (lane & 15);
            const bf16x8 bkh = *(const bf16x8*)(lds + KHI + swz(brow, kcol));
            const bf16x8 bkl = *(const bf16x8*)(lds + KLO + swz(brow, kcol));
            f32x4 c = acc[j];
            c = __builtin_amdgcn_mfma_f32_16x16x32_bf16(aqh, bkh, c, 0, 0, 0);
            c = __builtin_amdgcn_mfma_f32_16x16x32_bf16(aqh, bkl, c, 0, 0, 0);
            c = __builtin_amdgcn_mfma_f32_16x16x32_bf16(aql, bkh, c, 0, 0, 0);
            acc[j] = c;
        }
    }

    // ---- softmax over x. Row r of lane: h = 16ws + (l>>4)*4 + r. ----
    float p[4][4], invs[4];
    #pragma unroll
    for (int r = 0; r < 4; ++r) {
        float m = fmaxf(fmaxf(acc[0][r], acc[1][r]), fmaxf(acc[2][r], acc[3][r]));
        m = fmaxf(m, __shfl_xor(m, 1));
        m = fmaxf(m, __shfl_xor(m, 2));
        m = fmaxf(m, __shfl_xor(m, 4));
        m = fmaxf(m, __shfl_xor(m, 8));
        float s = 0.f;
        #pragma unroll
        for (int j = 0; j < 4; ++j) { p[j][r] = __expf(acc[j][r] - m); s += p[j][r]; }
        s += __shfl_xor(s, 1);
        s += __shfl_xor(s, 2);
        s += __shfl_xor(s, 4);
        s += __shfl_xor(s, 8);
        invs[r] = 1.f / s;
    }

    __syncthreads();   // QK reads of q planes done -> safe to overwrite with P

    // ---- write unnormalized P (hi only) into QHI plane, own strip rows ----
    #pragma unroll
    for (int r = 0; r < 4; ++r) {
        const int row = wsx * 16 + (lane >> 4) * 4 + r;
        #pragma unroll
        for (int j = 0; j < 4; ++j) {
            const int col = j * 16 + (lane & 15);
            *(short*)(lds + QHI + swz(row, col)) = f2bf(p[j][r]);
        }
    }
    __syncthreads();

    // ---- PV: wv[h][w] = sum_x P[h][x] V[x][w]  (1 MFMA per frag) ----
    f32x4 o_[4];
    #pragma unroll
    for (int j = 0; j < 4; ++j) o_[j] = (f32x4){0.f, 0.f, 0.f, 0.f};

    #pragma unroll
    for (int kk = 0; kk < 2; ++kk) {
        const int kcol = kk * 32 + (lane >> 4) * 8;
        const bf16x8 aph = *(const bf16x8*)(lds + QHI + swz(arow, kcol));
        #pragma unroll
        for (int j = 0; j < 4; ++j) {
            const int brow = j * 16 + (lane & 15);
            const bf16x8 bvh = *(const bf16x8*)(lds + VT + vswz(brow, kcol));
            o_[j] = __builtin_amdgcn_mfma_f32_16x16x32_bf16(aph, bvh, o_[j], 0, 0, 0);
        }
    }

    // ---- epilogue: normalize, split-pack u32, store over k slab ----
    #pragma unroll
    for (int r = 0; r < 4; ++r) {
        const int h = wsx * 16 + (lane >> 4) * 4 + r;
        #pragma unroll
        for (int j = 0; j < 4; ++j) {
            const float val = o_[j][r] * invs[r];
            const short hh = f2bf(val);
            const short ll = f2bf(val - bf2f(hh));
            kpk[base + (size_t)h * 64 + j * 16 + (lane & 15)] =
                (unsigned)(unsigned short)hh | ((unsigned)(unsigned short)ll << 16);
        }
    }
}

// ---------------------------------------------------------------------------
// fused tail: out = relu(W2 * relu(W1 * wv + b1) + b2). wv arrives packed u32.
// ---------------------------------------------------------------------------
__global__ __launch_bounds__(512, 4) void tail_fused_kernel(
    const unsigned* __restrict__ xpk,
    const short* __restrict__ wsp,           // w1 at +3*131072, w2 at +4*131072
    const float* __restrict__ b1, const float* __restrict__ b2,
    float* __restrict__ out)
{
    __shared__ char lds[65536];
    const int tid  = threadIdx.x;
    const int lane = tid & 63;
    const int wave = tid >> 6;
    const size_t boff = (size_t)blockIdx.y * ((size_t)CC * DHWC);
    const int sT = blockIdx.x * 64;
    const int n_l = lane & 15;
    const int m4  = (lane >> 4) * 4;

    f32x4 acc[2][4];

    // ---- phase A: GEMM1 over staged wv ----
    stage_u32(xpk + boff + sT, lds, tid);
    __syncthreads();
    #pragma unroll
    for (int f = 0; f < 2; ++f)
        #pragma unroll
        for (int j = 0; j < 4; ++j) acc[f][j] = (f32x4){0.f, 0.f, 0.f, 0.f};
    gemm256(lds, wsp + 3 * 131072, wsp + 3 * 131072 + 65536, wave, lane, acc);
    __syncthreads();   // all GEMM1 LDS reads done

    // ---- phase B: a = relu(acc + b1) -> split bf16 into LDS [s][256] ----
    #pragma unroll
    for (int f = 0; f < 2; ++f) {
        #pragma unroll
        for (int r = 0; r < 4; ++r) {
            const int o = wave * 32 + f * 16 + (lane >> 4) * 4 + r;
            const float bv = b1[o];
            #pragma unroll
            for (int j = 0; j < 4; ++j) {
                const int s = j * 16 + (lane & 15);
                const float val = fmaxf(acc[f][j][r] + bv, 0.f);
                const short h = f2bf(val);
                const int off = swz512(s, o);
                *(short*)(lds + off) = h;
                *(short*)(lds + 32768 + off) = f2bf(val - bf2f(h));
            }
        }
    }
    __syncthreads();

    // ---- phase C: GEMM2 ----
    #pragma unroll
    for (int f = 0; f < 2; ++f)
        #pragma unroll
        for (int j = 0; j < 4; ++j) acc[f][j] = (f32x4){0.f, 0.f, 0.f, 0.f};
    gemm256(lds, wsp + 4 * 131072, wsp + 4 * 131072 + 65536, wave, lane, acc);

    // ---- epilogue ----
    float* ob = out + boff + sT;
    #pragma unroll
    for (int f = 0; f < 2; ++f) {
        #pragma unroll
        for (int r = 0; r < 4; ++r) {
            const int o = wave * 32 + f * 16 + m4 + r;
            const float bv = b2[o];
            #pragma unroll
            for (int j = 0; j < 4; ++j)
                ob[(size_t)o * DHWC + j * 16 + n_l] = fmaxf(acc[f][j][r] + bv, 0.f);
        }
    }
}

// ---------------------------------------------------------------------------
// Pipeline: prep_w -> qkv -> attn -> tail.
// ws: q_packed (N u32) | k_packed (N u32, becomes wv in-place) | weights.
// d_out: v (N shorts) during attn, then final fp32 output.
// ---------------------------------------------------------------------------
extern "C" void kernel_launch(void* const* d_in, const int* in_sizes, int n_in,
                              void* d_out, int out_size, void* d_ws, size_t ws_size,
                              hipStream_t stream)
{
    const float* eeg    = (const float*)d_in[0];
    const float* img    = (const float*)d_in[1];
    const float* q_w    = (const float*)d_in[2];
    const float* q_b    = (const float*)d_in[3];
    const float* k_w    = (const float*)d_in[4];
    const float* k_b    = (const float*)d_in[5];
    const float* v_w    = (const float*)d_in[6];
    const float* v_b    = (const float*)d_in[7];
    const float* attn_w = (const float*)d_in[8];
    const float* attn_b = (const float*)d_in[9];
    const float* out_w  = (const float*)d_in[10];
    const float* out_b  = (const float*)d_in[11];

    const size_t N = (size_t)NBC * CC * DHWC;
    unsigned* qpk = (unsigned*)d_ws;
    unsigned* kpk = qpk + N;
    short*    wsp = (short*)(kpk + N);
    short*    vsh = (short*)d_out;
    float*    outp = (float*)d_out;

    hipLaunchKernelGGL(prep_w_kernel, dim3(16, 8, 5), dim3(64), 0, stream,
                       q_w, k_w, v_w, attn_w, out_w, wsp);

    hipLaunchKernelGGL(qkv_kernel, dim3(DHWC / 64, NBC), dim3(512), 0, stream,
                       eeg, img, wsp, q_b, k_b, v_b, qpk, kpk, vsh);

    hipLaunchKernelGGL(attn_mfma_kernel, dim3(NBC * CC * 16), dim3(256), 0, stream,
                       qpk, kpk, vsh);

    hipLaunchKernelGGL(tail_fused_kernel, dim3(DHWC / 64, NBC), dim3(512), 0, stream,
                       kpk, wsp, attn_b, out_b, outp);
}

// Round 6
// 417.442 us; speedup vs baseline: 1.2811x; 1.2811x over previous
//
#include <hip/hip_runtime.h>

#define CC   256
#define DHWC 65536          // D*H*W
#define NBC  2              // batch

typedef __attribute__((ext_vector_type(8))) short bf16x8;
typedef __attribute__((ext_vector_type(4))) short bf16x4;
typedef __attribute__((ext_vector_type(4))) float f32x4;

// ---- bf16 split helpers (branchless, bit-level, RTN-even) --------------------
__device__ __forceinline__ short f2bf(float x) {
    unsigned u = __builtin_bit_cast(unsigned, x);
    unsigned r = (u + 0x7fffu + ((u >> 16) & 1u)) >> 16;
    return (short)r;
}
__device__ __forceinline__ float bf2f(short h) {
    unsigned u = ((unsigned)(unsigned short)h) << 16;
    return __builtin_bit_cast(float, u);
}

// swizzled byte offset into a [64 r][64 c] bf16 LDS plane (row stride 128 B).
__device__ __forceinline__ int swz(int r, int c) {
    return (r * 128 + c * 2) ^ ((r & 7) << 4);
}
// richer swizzle for the V^T plane (write pattern is rows at stride 4)
__device__ __forceinline__ int vswz(int r, int c) {
    return (r * 128 + c * 2) ^ (((r ^ (r >> 3)) & 7) << 4);
}
// swizzled byte offset into a [64 s][256 k] bf16 LDS plane (row stride 512 B).
__device__ __forceinline__ int swz512(int s, int k) {
    return (s * 512 + k * 2) ^ ((s & 7) << 4);
}

// ---------------------------------------------------------------------------
// prep: split 5 weight matrices [256][256] fp32 into hi/lo bf16 planes stored
// fragment-major for mfma_f32_16x16x32_bf16 A-operand. Matrix m: hi at
// wsp + m*131072, lo at +65536.
// ---------------------------------------------------------------------------
__global__ void prep_w_kernel(const float* __restrict__ q_w, const float* __restrict__ k_w,
                              const float* __restrict__ v_w, const float* __restrict__ attn_w,
                              const float* __restrict__ out_w, short* __restrict__ wsp)
{
    const int l  = threadIdx.x;          // 64
    const int fo = blockIdx.x;           // 16
    const int t  = blockIdx.y;           // 8
    const int m  = blockIdx.z;           // 5
    const float* w = (m == 0) ? q_w : (m == 1) ? k_w : (m == 2) ? v_w
                   : (m == 3) ? attn_w : out_w;
    short* whi = wsp + (size_t)m * 131072;
    short* wlo = whi + 65536;

    const int o = fo * 16 + (l & 15);
    const int k = t * 32 + (l >> 4) * 8;

    bf16x8 hv, lv;
    #pragma unroll
    for (int r = 0; r < 8; ++r) {
        const float x = w[o * 256 + k + r];
        const short h = f2bf(x);
        hv[r] = h;
        lv[r] = f2bf(x - bf2f(h));
    }
    const int idx = (fo * 8 + t) * 64 + l;
    *(bf16x8*)(whi + idx * 8) = hv;
    *(bf16x8*)(wlo + idx * 8) = lv;
}

// ---------------------------------------------------------------------------
// conv1x1 via split-bf16 MFMA, double-buffered 64-K-step pipeline (round-4).
// ---------------------------------------------------------------------------
__global__ __launch_bounds__(512, 4) void conv_mfma_kernel(
    const float* __restrict__ x, const short* __restrict__ whi,
    const short* __restrict__ wlo, const float* __restrict__ bias,
    float* __restrict__ out, const int do_relu)
{
    __shared__ bf16x8 xhi[2][512];   // [buf][64 s][64 k] bf16, 8 KB each
    __shared__ bf16x8 xlo[2][512];

    const int tid  = threadIdx.x;
    const int lane = tid & 63;
    const int wave = tid >> 6;            // 0..7
    const size_t boff = (size_t)blockIdx.y * ((size_t)CC * DHWC);
    const int sT = blockIdx.x * 64;
    const float* xb = x + boff + sT;
    const bf16x8* whf = (const bf16x8*)whi;
    const bf16x8* wlf = (const bf16x8*)wlo;

    f32x4 acc[2][4];
    #pragma unroll
    for (int f = 0; f < 2; ++f)
        #pragma unroll
        for (int j = 0; j < 4; ++j)
            acc[f][j] = (f32x4){0.f, 0.f, 0.f, 0.f};

    const int s_l = tid & 63;
    const int k8  = tid >> 6;

    float xr[8];
    #pragma unroll
    for (int r = 0; r < 8; ++r)
        xr[r] = xb[(size_t)(k8 * 8 + r) * DHWC + s_l];
    {
        bf16x8 hv, lv;
        #pragma unroll
        for (int r = 0; r < 8; ++r) {
            const short h = f2bf(xr[r]);
            hv[r] = h;
            lv[r] = f2bf(xr[r] - bf2f(h));
        }
        *(bf16x8*)((char*)xhi[0] + swz(s_l, k8 * 8)) = hv;
        *(bf16x8*)((char*)xlo[0] + swz(s_l, k8 * 8)) = lv;
    }

    #pragma unroll
    for (int t = 0; t < 4; ++t) {
        if (t < 3) {
            #pragma unroll
            for (int r = 0; r < 8; ++r)
                xr[r] = xb[(size_t)((t + 1) * 64 + k8 * 8 + r) * DHWC + s_l];
        }
        __syncthreads();

        const char* bhib = (const char*)xhi[t & 1];
        const char* blob = (const char*)xlo[t & 1];
        #pragma unroll
        for (int kk = 0; kk < 2; ++kk) {
            bf16x8 a1h[2], a1l[2];
            #pragma unroll
            for (int f = 0; f < 2; ++f) {
                const int idx = ((wave * 2 + f) * 8 + 2 * t + kk) * 64 + lane;
                a1h[f] = whf[idx];
                a1l[f] = wlf[idx];
            }
            bf16x8 bh[4], bl[4];
            #pragma unroll
            for (int j = 0; j < 4; ++j) {
                const int s = j * 16 + (lane & 15);
                const int k = kk * 32 + (lane >> 4) * 8;
                bh[j] = *(const bf16x8*)(bhib + swz(s, k));
                bl[j] = *(const bf16x8*)(blob + swz(s, k));
            }
            #pragma unroll
            for (int f = 0; f < 2; ++f)
                #pragma unroll
                for (int j = 0; j < 4; ++j) {
                    f32x4 c = acc[f][j];
                    c = __builtin_amdgcn_mfma_f32_16x16x32_bf16(a1h[f], bh[j], c, 0, 0, 0);
                    c = __builtin_amdgcn_mfma_f32_16x16x32_bf16(a1h[f], bl[j], c, 0, 0, 0);
                    c = __builtin_amdgcn_mfma_f32_16x16x32_bf16(a1l[f], bh[j], c, 0, 0, 0);
                    acc[f][j] = c;
                }
        }

        if (t < 3) {
            bf16x8 hv, lv;
            #pragma unroll
            for (int r = 0; r < 8; ++r) {
                const short h = f2bf(xr[r]);
                hv[r] = h;
                lv[r] = f2bf(xr[r] - bf2f(h));
            }
            *(bf16x8*)((char*)xhi[(t + 1) & 1] + swz(s_l, k8 * 8)) = hv;
            *(bf16x8*)((char*)xlo[(t + 1) & 1] + swz(s_l, k8 * 8)) = lv;
        }
    }

    float* ob = out + boff + sT;
    const int n_l = lane & 15;
    const int m4  = (lane >> 4) * 4;
    #pragma unroll
    for (int f = 0; f < 2; ++f) {
        #pragma unroll
        for (int r = 0; r < 4; ++r) {
            const int o = wave * 32 + f * 16 + m4 + r;
            const float bv = bias[o];
            #pragma unroll
            for (int j = 0; j < 4; ++j) {
                float val = acc[f][j][r] + bv;
                if (do_relu) val = fmaxf(val, 0.f);
                ob[(size_t)o * DHWC + j * 16 + n_l] = val;
            }
        }
    }
}

// ---------------------------------------------------------------------------
// kv conv: k = Wk*img + kb (fp32), v = Wv*img + vb (bf16 shorts).
// One double-buffered img staging feeds BOTH GEMMs (B-frags read once,
// consumed by 6 MFMAs). Same pipeline skeleton as conv_mfma_kernel.
// ---------------------------------------------------------------------------
__global__ __launch_bounds__(512, 4) void kv_conv_kernel(
    const float* __restrict__ img,
    const short* __restrict__ wkhi, const short* __restrict__ wklo,
    const short* __restrict__ wvhi, const short* __restrict__ wvlo,
    const float* __restrict__ kb, const float* __restrict__ vb,
    float* __restrict__ kout, short* __restrict__ vout)
{
    __shared__ bf16x8 xhi[2][512];
    __shared__ bf16x8 xlo[2][512];

    const int tid  = threadIdx.x;
    const int lane = tid & 63;
    const int wave = tid >> 6;
    const size_t boff = (size_t)blockIdx.y * ((size_t)CC * DHWC);
    const int sT = blockIdx.x * 64;
    const float* xb = img + boff + sT;
    const bf16x8* wkhf = (const bf16x8*)wkhi;
    const bf16x8* wklf = (const bf16x8*)wklo;
    const bf16x8* wvhf = (const bf16x8*)wvhi;
    const bf16x8* wvlf = (const bf16x8*)wvlo;

    f32x4 acck[2][4], accv[2][4];
    #pragma unroll
    for (int f = 0; f < 2; ++f)
        #pragma unroll
        for (int j = 0; j < 4; ++j) {
            acck[f][j] = (f32x4){0.f, 0.f, 0.f, 0.f};
            accv[f][j] = (f32x4){0.f, 0.f, 0.f, 0.f};
        }

    const int s_l = tid & 63;
    const int k8  = tid >> 6;

    float xr[8];
    #pragma unroll
    for (int r = 0; r < 8; ++r)
        xr[r] = xb[(size_t)(k8 * 8 + r) * DHWC + s_l];
    {
        bf16x8 hv, lv;
        #pragma unroll
        for (int r = 0; r < 8; ++r) {
            const short h = f2bf(xr[r]);
            hv[r] = h;
            lv[r] = f2bf(xr[r] - bf2f(h));
        }
        *(bf16x8*)((char*)xhi[0] + swz(s_l, k8 * 8)) = hv;
        *(bf16x8*)((char*)xlo[0] + swz(s_l, k8 * 8)) = lv;
    }

    #pragma unroll
    for (int t = 0; t < 4; ++t) {
        if (t < 3) {
            #pragma unroll
            for (int r = 0; r < 8; ++r)
                xr[r] = xb[(size_t)((t + 1) * 64 + k8 * 8 + r) * DHWC + s_l];
        }
        __syncthreads();

        const char* bhib = (const char*)xhi[t & 1];
        const char* blob = (const char*)xlo[t & 1];
        #pragma unroll
        for (int kk = 0; kk < 2; ++kk) {
            // resident A-frags for both weight matrices (L1-hot)
            bf16x8 akh[2], akl[2], avh[2], avl[2];
            #pragma unroll
            for (int f = 0; f < 2; ++f) {
                const int idx = ((wave * 2 + f) * 8 + 2 * t + kk) * 64 + lane;
                akh[f] = wkhf[idx];
                akl[f] = wklf[idx];
                avh[f] = wvhf[idx];
                avl[f] = wvlf[idx];
            }
            #pragma unroll
            for (int j = 0; j < 4; ++j) {     // transient B pair
                const int s = j * 16 + (lane & 15);
                const int k = kk * 32 + (lane >> 4) * 8;
                const bf16x8 bh = *(const bf16x8*)(bhib + swz(s, k));
                const bf16x8 bl = *(const bf16x8*)(blob + swz(s, k));
                #pragma unroll
                for (int f = 0; f < 2; ++f) {
                    f32x4 c = acck[f][j];
                    c = __builtin_amdgcn_mfma_f32_16x16x32_bf16(akh[f], bh, c, 0, 0, 0);
                    c = __builtin_amdgcn_mfma_f32_16x16x32_bf16(akh[f], bl, c, 0, 0, 0);
                    c = __builtin_amdgcn_mfma_f32_16x16x32_bf16(akl[f], bh, c, 0, 0, 0);
                    acck[f][j] = c;
                    f32x4 d = accv[f][j];
                    d = __builtin_amdgcn_mfma_f32_16x16x32_bf16(avh[f], bh, d, 0, 0, 0);
                    d = __builtin_amdgcn_mfma_f32_16x16x32_bf16(avh[f], bl, d, 0, 0, 0);
                    d = __builtin_amdgcn_mfma_f32_16x16x32_bf16(avl[f], bh, d, 0, 0, 0);
                    accv[f][j] = d;
                }
            }
        }

        if (t < 3) {
            bf16x8 hv, lv;
            #pragma unroll
            for (int r = 0; r < 8; ++r) {
                const short h = f2bf(xr[r]);
                hv[r] = h;
                lv[r] = f2bf(xr[r] - bf2f(h));
            }
            *(bf16x8*)((char*)xhi[(t + 1) & 1] + swz(s_l, k8 * 8)) = hv;
            *(bf16x8*)((char*)xlo[(t + 1) & 1] + swz(s_l, k8 * 8)) = lv;
        }
    }

    float* ko = kout + boff + sT;
    short* vo = vout + boff + sT;
    const int n_l = lane & 15;
    const int m4  = (lane >> 4) * 4;
    #pragma unroll
    for (int f = 0; f < 2; ++f) {
        #pragma unroll
        for (int r = 0; r < 4; ++r) {
            const int o = wave * 32 + f * 16 + m4 + r;
            const float kbv = kb[o];
            const float vbv = vb[o];
            #pragma unroll
            for (int j = 0; j < 4; ++j) {
                ko[(size_t)o * DHWC + j * 16 + n_l] = acck[f][j][r] + kbv;
                vo[(size_t)o * DHWC + j * 16 + n_l] = f2bf(accv[f][j][r] + vbv);
            }
        }
    }
}

// ---------------------------------------------------------------------------
// attention. One block (256 thr = 4 waves) per (b,c,d) slab.
// q,k fp32 (split at stage); v bf16 shorts (transpose-stage only).
// Writes wv fp32 IN-PLACE over the q buffer (slab staged before write).
// ---------------------------------------------------------------------------
__global__ __launch_bounds__(256, 4) void attn_mfma_kernel(
    const float* q, const float* __restrict__ kg,
    const short* __restrict__ vsh, float* wv)
{
    __shared__ char lds[40960];
    const int QHI = 0, QLO = 8192, KHI = 16384, KLO = 24576, VT = 32768;

    const int tid  = threadIdx.x;
    const int lane = tid & 63;
    const int wsx  = tid >> 6;           // wave 0..3
    const size_t base = (size_t)blockIdx.x * 4096;

    // ---- stage q, k row-major split-bf16 ----
    {
        const int r  = tid >> 2;         // 0..63
        const int cb = (tid & 3) * 16;
        #pragma unroll
        for (int half = 0; half < 2; ++half) {
            const int c = cb + half * 8;
            const float4 qa = *(const float4*)(q  + base + r * 64 + c);
            const float4 qb = *(const float4*)(q  + base + r * 64 + c + 4);
            const float4 ka = *(const float4*)(kg + base + r * 64 + c);
            const float4 kb = *(const float4*)(kg + base + r * 64 + c + 4);
            bf16x8 qh, ql, kh, kl;
            #pragma unroll
            for (int e = 0; e < 4; ++e) {
                float xq = ((const float*)&qa)[e];
                short h = f2bf(xq); qh[e] = h; ql[e] = f2bf(xq - bf2f(h));
                xq = ((const float*)&qb)[e];
                h = f2bf(xq); qh[e + 4] = h; ql[e + 4] = f2bf(xq - bf2f(h));
                float xk = ((const float*)&ka)[e];
                h = f2bf(xk); kh[e] = h; kl[e] = f2bf(xk - bf2f(h));
                xk = ((const float*)&kb)[e];
                h = f2bf(xk); kh[e + 4] = h; kl[e + 4] = f2bf(xk - bf2f(h));
            }
            const int off = swz(r, c);
            *(bf16x8*)(lds + QHI + off) = qh;
            *(bf16x8*)(lds + QLO + off) = ql;
            *(bf16x8*)(lds + KHI + off) = kh;
            *(bf16x8*)(lds + KLO + off) = kl;
        }
        // ---- stage V transposed from shorts (no conversion) ----
        const short* vpl = vsh + base;
        const int x0 = (tid >> 4) * 4;
        const int w0 = (tid & 15) * 4;
        bf16x4 vr[4];
        #pragma unroll
        for (int i = 0; i < 4; ++i)
            vr[i] = *(const bf16x4*)(vpl + (x0 + i) * 64 + w0);
        #pragma unroll
        for (int j = 0; j < 4; ++j) {
            bf16x4 tv;
            #pragma unroll
            for (int i = 0; i < 4; ++i) tv[i] = vr[i][j];
            *(bf16x4*)(lds + VT + vswz(w0 + j, x0)) = tv;
        }
    }
    __syncthreads();

    // ---- QK^T: S[h][x] for h in own strip (3-term split) ----
    f32x4 acc[4];
    #pragma unroll
    for (int j = 0; j < 4; ++j) acc[j] = (f32x4){0.f, 0.f, 0.f, 0.f};

    const int arow = wsx * 16 + (lane & 15);
    #pragma unroll
    for (int kk = 0; kk < 2; ++kk) {
        const int kcol = kk * 32 + (lane >> 4) * 8;
        const bf16x8 aqh = *(const bf16x8*)(lds + QHI + swz(arow, kcol));
        const bf16x8 aql = *(const bf16x8*)(lds + QLO + swz(arow, kcol));
        #pragma unroll
        for (int j = 0; j < 4; ++j) {
            const int brow = j * 16 + (lane & 15);
            const bf16x8 bkh = *(const bf16x8*)(lds + KHI + swz(brow, kcol));
            const bf16x8 bkl = *(const bf16x8*)(lds + KLO + swz(brow, kcol));
            f32x4 c = acc[j];
            c = __builtin_amdgcn_mfma_f32_16x16x32_bf16(aqh, bkh, c, 0, 0, 0);
            c = __builtin_amdgcn_mfma_f32_16x16x32_bf16(aqh, bkl, c, 0, 0, 0);
            c = __builtin_amdgcn_mfma_f32_16x16x32_bf16(aql, bkh, c, 0, 0, 0);
            acc[j] = c;
        }
    }

    // ---- softmax over x. Row r of lane: h = 16ws + (l>>4)*4 + r. ----
    float p[4][4], invs[4];
    #pragma unroll
    for (int r = 0; r < 4; ++r) {
        float m = fmaxf(fmaxf(acc[0][r], acc[1][r]), fmaxf(acc[2][r], acc[3][r]));
        m = fmaxf(m, __shfl_xor(m, 1));
        m = fmaxf(m, __shfl_xor(m, 2));
        m = fmaxf(m, __shfl_xor(m, 4));
        m = fmaxf(m, __shfl_xor(m, 8));
        float s = 0.f;
        #pragma unroll
        for (int j = 0; j < 4; ++j) { p[j][r] = __expf(acc[j][r] - m); s += p[j][r]; }
        s += __shfl_xor(s, 1);
        s += __shfl_xor(s, 2);
        s += __shfl_xor(s, 4);
        s += __shfl_xor(s, 8);
        invs[r] = 1.f / s;
    }

    __syncthreads();   // QK reads of q planes done -> safe to overwrite with P

    // ---- write unnormalized P (hi only) into QHI plane, own strip rows ----
    #pragma unroll
    for (int r = 0; r < 4; ++r) {
        const int row = wsx * 16 + (lane >> 4) * 4 + r;
        #pragma unroll
        for (int j = 0; j < 4; ++j) {
            const int col = j * 16 + (lane & 15);
            *(short*)(lds + QHI + swz(row, col)) = f2bf(p[j][r]);
        }
    }
    __syncthreads();

    // ---- PV: wv[h][w] = sum_x P[h][x] V[x][w]  (1 MFMA per frag) ----
    f32x4 o_[4];
    #pragma unroll
    for (int j = 0; j < 4; ++j) o_[j] = (f32x4){0.f, 0.f, 0.f, 0.f};

    #pragma unroll
    for (int kk = 0; kk < 2; ++kk) {
        const int kcol = kk * 32 + (lane >> 4) * 8;
        const bf16x8 aph = *(const bf16x8*)(lds + QHI + swz(arow, kcol));
        #pragma unroll
        for (int j = 0; j < 4; ++j) {
            const int brow = j * 16 + (lane & 15);
            const bf16x8 bvh = *(const bf16x8*)(lds + VT + vswz(brow, kcol));
            o_[j] = __builtin_amdgcn_mfma_f32_16x16x32_bf16(aph, bvh, o_[j], 0, 0, 0);
        }
    }

    // ---- epilogue: normalize and store (in-place over q slab) ----
    #pragma unroll
    for (int r = 0; r < 4; ++r) {
        const int h = wsx * 16 + (lane >> 4) * 4 + r;
        #pragma unroll
        for (int j = 0; j < 4; ++j)
            wv[base + (size_t)h * 64 + j * 16 + (lane & 15)] = o_[j][r] * invs[r];
    }
}

// ---------------------------------------------------------------------------
// fused tail: out = relu(W2 * relu(W1 * wv + b1) + b2) (round-4 verbatim).
// ---------------------------------------------------------------------------
__global__ __launch_bounds__(512, 4) void tail_fused_kernel(
    const float* __restrict__ x,
    const short* __restrict__ w1hi, const short* __restrict__ w1lo,
    const float* __restrict__ b1,
    const short* __restrict__ w2hi, const short* __restrict__ w2lo,
    const float* __restrict__ b2,
    float* __restrict__ out)
{
    __shared__ char lds[65536];
    const int tid  = threadIdx.x;
    const int lane = tid & 63;
    const int wave = tid >> 6;
    const size_t boff = (size_t)blockIdx.y * ((size_t)CC * DHWC);
    const int sT = blockIdx.x * 64;
    const float* xb = x + boff + sT;
    const bf16x8* w1hf = (const bf16x8*)w1hi;
    const bf16x8* w1lf = (const bf16x8*)w1lo;

    f32x4 acc[2][4];
    #pragma unroll
    for (int f = 0; f < 2; ++f)
        #pragma unroll
        for (int j = 0; j < 4; ++j)
            acc[f][j] = (f32x4){0.f, 0.f, 0.f, 0.f};

    const int s_l = tid & 63;
    const int k8  = tid >> 6;

    float xr[8];
    #pragma unroll
    for (int r = 0; r < 8; ++r)
        xr[r] = xb[(size_t)(k8 * 8 + r) * DHWC + s_l];
    {
        bf16x8 hv, lv;
        #pragma unroll
        for (int r = 0; r < 8; ++r) {
            const short h = f2bf(xr[r]);
            hv[r] = h;
            lv[r] = f2bf(xr[r] - bf2f(h));
        }
        *(bf16x8*)(lds + swz(s_l, k8 * 8)) = hv;
        *(bf16x8*)(lds + 8192 + swz(s_l, k8 * 8)) = lv;
    }

    #pragma unroll
    for (int t = 0; t < 4; ++t) {
        if (t < 3) {
            #pragma unroll
            for (int r = 0; r < 8; ++r)
                xr[r] = xb[(size_t)((t + 1) * 64 + k8 * 8 + r) * DHWC + s_l];
        }
        __syncthreads();

        const char* bhib = lds + (t & 1) * 16384;
        const char* blob = bhib + 8192;
        #pragma unroll
        for (int kk = 0; kk < 2; ++kk) {
            bf16x8 a1h[2], a1l[2];
            #pragma unroll
            for (int f = 0; f < 2; ++f) {
                const int idx = ((wave * 2 + f) * 8 + 2 * t + kk) * 64 + lane;
                a1h[f] = w1hf[idx];
                a1l[f] = w1lf[idx];
            }
            bf16x8 bh[4], bl[4];
            #pragma unroll
            for (int j = 0; j < 4; ++j) {
                const int s = j * 16 + (lane & 15);
                const int k = kk * 32 + (lane >> 4) * 8;
                bh[j] = *(const bf16x8*)(bhib + swz(s, k));
                bl[j] = *(const bf16x8*)(blob + swz(s, k));
            }
            #pragma unroll
            for (int f = 0; f < 2; ++f)
                #pragma unroll
                for (int j = 0; j < 4; ++j) {
                    f32x4 c = acc[f][j];
                    c = __builtin_amdgcn_mfma_f32_16x16x32_bf16(a1h[f], bh[j], c, 0, 0, 0);
                    c = __builtin_amdgcn_mfma_f32_16x16x32_bf16(a1h[f], bl[j], c, 0, 0, 0);
                    c = __builtin_amdgcn_mfma_f32_16x16x32_bf16(a1l[f], bh[j], c, 0, 0, 0);
                    acc[f][j] = c;
                }
        }

        if (t < 3) {
            bf16x8 hv, lv;
            #pragma unroll
            for (int r = 0; r < 8; ++r) {
                const short h = f2bf(xr[r]);
                hv[r] = h;
                lv[r] = f2bf(xr[r] - bf2f(h));
            }
            *(bf16x8*)(lds + ((t + 1) & 1) * 16384 + swz(s_l, k8 * 8)) = hv;
            *(bf16x8*)(lds + ((t + 1) & 1) * 16384 + 8192 + swz(s_l, k8 * 8)) = lv;
        }
    }

    // ---- phase B: a = relu(acc + b1) -> split bf16 into LDS [s][256] ----
    __syncthreads();
    #pragma unroll
    for (int f = 0; f < 2; ++f) {
        #pragma unroll
        for (int r = 0; r < 4; ++r) {
            const int o = wave * 32 + f * 16 + (lane >> 4) * 4 + r;
            const float bv = b1[o];
            #pragma unroll
            for (int j = 0; j < 4; ++j) {
                const int s = j * 16 + (lane & 15);
                const float val = fmaxf(acc[f][j][r] + bv, 0.f);
                const short h = f2bf(val);
                const int off = swz512(s, o);
                *(short*)(lds + off) = h;
                *(short*)(lds + 32768 + off) = f2bf(val - bf2f(h));
            }
        }
    }
    __syncthreads();

    // ---- phase C: GEMM2, W2 streamed from L2 ----
    f32x4 acc2[2][4];
    #pragma unroll
    for (int f = 0; f < 2; ++f)
        #pragma unroll
        for (int j = 0; j < 4; ++j)
            acc2[f][j] = (f32x4){0.f, 0.f, 0.f, 0.f};

    const bf16x8* w2hf = (const bf16x8*)w2hi;
    const bf16x8* w2lf = (const bf16x8*)w2lo;
    #pragma unroll
    for (int t2 = 0; t2 < 8; ++t2) {
        bf16x8 a2h[2], a2l[2];
        #pragma unroll
        for (int f = 0; f < 2; ++f) {
            const int idx = ((wave * 2 + f) * 8 + t2) * 64 + lane;
            a2h[f] = w2hf[idx];
            a2l[f] = w2lf[idx];
        }
        bf16x8 bh[4], bl[4];
        #pragma unroll
        for (int j = 0; j < 4; ++j) {
            const int s = j * 16 + (lane & 15);
            const int k = t2 * 32 + (lane >> 4) * 8;
            const int off = swz512(s, k);
            bh[j] = *(const bf16x8*)(lds + off);
            bl[j] = *(const bf16x8*)(lds + 32768 + off);
        }
        #pragma unroll
        for (int f = 0; f < 2; ++f)
            #pragma unroll
            for (int j = 0; j < 4; ++j) {
                f32x4 c = acc2[f][j];
                c = __builtin_amdgcn_mfma_f32_16x16x32_bf16(a2h[f], bh[j], c, 0, 0, 0);
                c = __builtin_amdgcn_mfma_f32_16x16x32_bf16(a2h[f], bl[j], c, 0, 0, 0);
                c = __builtin_amdgcn_mfma_f32_16x16x32_bf16(a2l[f], bh[j], c, 0, 0, 0);
                acc2[f][j] = c;
            }
    }

    // ---- epilogue 2 ----
    float* ob = out + boff + sT;
    const int n_l = lane & 15;
    const int m4  = (lane >> 4) * 4;
    #pragma unroll
    for (int f = 0; f < 2; ++f) {
        #pragma unroll
        for (int r = 0; r < 4; ++r) {
            const int o = wave * 32 + f * 16 + m4 + r;
            const float bv = b2[o];
            #pragma unroll
            for (int j = 0; j < 4; ++j) {
                const float val = fmaxf(acc2[f][j][r] + bv, 0.f);
                ob[(size_t)o * DHWC + j * 16 + n_l] = val;
            }
        }
    }
}

// ---------------------------------------------------------------------------
// Pipeline: prep_w -> q=conv(eeg) ; {k,v}=kv_conv(img) -> attn -> tail.
// ws: qbuf (N f32, becomes wv in-place) | kbuf (N f32) | weights.
// d_out: v (N shorts) during attn, then final fp32 output.
// ---------------------------------------------------------------------------
extern "C" void kernel_launch(void* const* d_in, const int* in_sizes, int n_in,
                              void* d_out, int out_size, void* d_ws, size_t ws_size,
                              hipStream_t stream)
{
    const float* eeg    = (const float*)d_in[0];
    const float* img    = (const float*)d_in[1];
    const float* q_w    = (const float*)d_in[2];
    const float* q_b    = (const float*)d_in[3];
    const float* k_w    = (const float*)d_in[4];
    const float* k_b    = (const float*)d_in[5];
    const float* v_w    = (const float*)d_in[6];
    const float* v_b    = (const float*)d_in[7];
    const float* attn_w = (const float*)d_in[8];
    const float* attn_b = (const float*)d_in[9];
    const float* out_w  = (const float*)d_in[10];
    const float* out_b  = (const float*)d_in[11];

    const size_t N = (size_t)NBC * CC * DHWC;
    float* qbuf = (float*)d_ws;
    float* kbuf = qbuf + N;
    short* wsp  = (short*)(kbuf + N);
    short* vsh  = (short*)d_out;
    float* outp = (float*)d_out;

    hipLaunchKernelGGL(prep_w_kernel, dim3(16, 8, 5), dim3(64), 0, stream,
                       q_w, k_w, v_w, attn_w, out_w, wsp);

    const dim3 cgrid(DHWC / 64, NBC);

    hipLaunchKernelGGL(conv_mfma_kernel, cgrid, dim3(512), 0, stream,
                       eeg, wsp, wsp + 65536, q_b, qbuf, 0);

    hipLaunchKernelGGL(kv_conv_kernel, cgrid, dim3(512), 0, stream,
                       img, wsp + 131072, wsp + 131072 + 65536,
                       wsp + 2 * 131072, wsp + 2 * 131072 + 65536,
                       k_b, v_b, kbuf, vsh);

    hipLaunchKernelGGL(attn_mfma_kernel, dim3(NBC * CC * 16), dim3(256), 0, stream,
                       qbuf, kbuf, vsh, qbuf);

    hipLaunchKernelGGL(tail_fused_kernel, cgrid, dim3(512), 0, stream,
                       qbuf, wsp + 3 * 131072, wsp + 3 * 131072 + 65536, attn_b,
                       wsp + 4 * 131072, wsp + 4 * 131072 + 65536, out_b, outp);
}

// Round 7
// 410.112 us; speedup vs baseline: 1.3040x; 1.0179x over previous
//
#include <hip/hip_runtime.h>

#define CC   256
#define DHWC 65536          // D*H*W
#define NBC  2              // batch

typedef __attribute__((ext_vector_type(8))) short bf16x8;
typedef __attribute__((ext_vector_type(4))) short bf16x4;
typedef __attribute__((ext_vector_type(4))) float f32x4;

// ---- bf16 split helpers (branchless, bit-level, RTN-even) --------------------
__device__ __forceinline__ short f2bf(float x) {
    unsigned u = __builtin_bit_cast(unsigned, x);
    unsigned r = (u + 0x7fffu + ((u >> 16) & 1u)) >> 16;
    return (short)r;
}
__device__ __forceinline__ float bf2f(short h) {
    unsigned u = ((unsigned)(unsigned short)h) << 16;
    return __builtin_bit_cast(float, u);
}

// swizzled byte offset into a [R rows][64 c] bf16 LDS plane (row stride 128 B).
__device__ __forceinline__ int swz(int r, int c) {
    return (r * 128 + c * 2) ^ ((r & 7) << 4);
}
// richer swizzle for the V^T plane (write pattern is rows at stride 4)
__device__ __forceinline__ int vswz(int r, int c) {
    return (r * 128 + c * 2) ^ (((r ^ (r >> 3)) & 7) << 4);
}
// swizzled byte offset into a [128 s][256 k] bf16 LDS plane (row stride 512 B).
__device__ __forceinline__ int swz512(int s, int k) {
    return (s * 512 + k * 2) ^ ((s & 7) << 4);
}

// ---------------------------------------------------------------------------
// prep: split 5 weight matrices [256][256] fp32 into hi/lo bf16 planes stored
// fragment-major for mfma_f32_16x16x32_bf16 A-operand:
//   frag (fo = o/16, t = k/32): lane l holds W[fo*16 + (l&15)][t*32 + (l>>4)*8 + r]
// Matrix m: hi at wsp + m*131072, lo at +65536.
// ---------------------------------------------------------------------------
__global__ void prep_w_kernel(const float* __restrict__ q_w, const float* __restrict__ k_w,
                              const float* __restrict__ v_w, const float* __restrict__ attn_w,
                              const float* __restrict__ out_w, short* __restrict__ wsp)
{
    const int l  = threadIdx.x;          // 64
    const int fo = blockIdx.x;           // 16
    const int t  = blockIdx.y;           // 8
    const int m  = blockIdx.z;           // 5
    const float* w = (m == 0) ? q_w : (m == 1) ? k_w : (m == 2) ? v_w
                   : (m == 3) ? attn_w : out_w;
    short* whi = wsp + (size_t)m * 131072;
    short* wlo = whi + 65536;

    const int o = fo * 16 + (l & 15);
    const int k = t * 32 + (l >> 4) * 8;

    bf16x8 hv, lv;
    #pragma unroll
    for (int r = 0; r < 8; ++r) {
        const float x = w[o * 256 + k + r];
        const short h = f2bf(x);
        hv[r] = h;
        lv[r] = f2bf(x - bf2f(h));
    }
    const int idx = (fo * 8 + t) * 64 + l;
    *(bf16x8*)(whi + idx * 8) = hv;
    *(bf16x8*)(wlo + idx * 8) = lv;
}

// ---------------------------------------------------------------------------
// conv1x1, BN=128, 1024 thr = 16 waves; wave w owns o-strip [16w,16w+16).
// Double-buffered [128 s][64 k] hi/lo staging; split-bf16 3-MFMA.
// ---------------------------------------------------------------------------
__global__ __launch_bounds__(1024, 4) void conv_mfma_kernel(
    const float* __restrict__ x, const short* __restrict__ whi,
    const short* __restrict__ wlo, const float* __restrict__ bias,
    float* __restrict__ out, const int do_relu)
{
    __shared__ char lds[65536];   // buf b at b*32768: hi +0, lo +16384 ([128][64] bf16)

    const int tid  = threadIdx.x;
    const int lane = tid & 63;
    const int wave = tid >> 6;            // 0..15
    const size_t boff = (size_t)blockIdx.y * ((size_t)CC * DHWC);
    const int sT = blockIdx.x * 128;
    const float* xb = x + boff + sT;
    const bf16x8* whf = (const bf16x8*)whi;
    const bf16x8* wlf = (const bf16x8*)wlo;

    f32x4 acc[8];
    #pragma unroll
    for (int j = 0; j < 8; ++j) acc[j] = (f32x4){0.f, 0.f, 0.f, 0.f};

    const int s_l = tid & 127;
    const int k8  = tid >> 7;     // 0..7

    float xr[8];
    #pragma unroll
    for (int r = 0; r < 8; ++r)
        xr[r] = xb[(size_t)(k8 * 8 + r) * DHWC + s_l];
    {
        bf16x8 hv, lv;
        #pragma unroll
        for (int r = 0; r < 8; ++r) {
            const short h = f2bf(xr[r]);
            hv[r] = h;
            lv[r] = f2bf(xr[r] - bf2f(h));
        }
        const int off = swz(s_l, k8 * 8);
        *(bf16x8*)(lds + off) = hv;
        *(bf16x8*)(lds + 16384 + off) = lv;
    }

    #pragma unroll
    for (int t = 0; t < 4; ++t) {
        if (t < 3) {
            #pragma unroll
            for (int r = 0; r < 8; ++r)
                xr[r] = xb[(size_t)((t + 1) * 64 + k8 * 8 + r) * DHWC + s_l];
        }
        __syncthreads();

        const char* bhib = lds + (t & 1) * 32768;
        const char* blob = bhib + 16384;
        #pragma unroll
        for (int kk = 0; kk < 2; ++kk) {
            const int idx = (wave * 8 + 2 * t + kk) * 64 + lane;
            const bf16x8 a1h = whf[idx];
            const bf16x8 a1l = wlf[idx];
            #pragma unroll
            for (int j = 0; j < 8; ++j) {
                const int s = j * 16 + (lane & 15);
                const int k = kk * 32 + (lane >> 4) * 8;
                const bf16x8 bh = *(const bf16x8*)(bhib + swz(s, k));
                const bf16x8 bl = *(const bf16x8*)(blob + swz(s, k));
                f32x4 c = acc[j];
                c = __builtin_amdgcn_mfma_f32_16x16x32_bf16(a1h, bh, c, 0, 0, 0);
                c = __builtin_amdgcn_mfma_f32_16x16x32_bf16(a1h, bl, c, 0, 0, 0);
                c = __builtin_amdgcn_mfma_f32_16x16x32_bf16(a1l, bh, c, 0, 0, 0);
                acc[j] = c;
            }
        }

        if (t < 3) {
            bf16x8 hv, lv;
            #pragma unroll
            for (int r = 0; r < 8; ++r) {
                const short h = f2bf(xr[r]);
                hv[r] = h;
                lv[r] = f2bf(xr[r] - bf2f(h));
            }
            const int off = ((t + 1) & 1) * 32768 + swz(s_l, k8 * 8);
            *(bf16x8*)(lds + off) = hv;
            *(bf16x8*)(lds + 16384 + off) = lv;
        }
    }

    float* ob = out + boff + sT;
    const int n_l = lane & 15;
    const int m4  = (lane >> 4) * 4;
    #pragma unroll
    for (int r = 0; r < 4; ++r) {
        const int o = wave * 16 + m4 + r;
        const float bv = bias[o];
        #pragma unroll
        for (int j = 0; j < 8; ++j) {
            float val = acc[j][r] + bv;
            if (do_relu) val = fmaxf(val, 0.f);
            ob[(size_t)o * DHWC + j * 16 + n_l] = val;
        }
    }
}

// ---------------------------------------------------------------------------
// kv conv, BN=128: k = Wk*img + kb (fp32), v = Wv*img + vb (bf16 shorts).
// One staging feeds both GEMMs (each B-frag pair feeds 6 MFMAs).
// ---------------------------------------------------------------------------
__global__ __launch_bounds__(1024, 4) void kv_conv_kernel(
    const float* __restrict__ img,
    const short* __restrict__ wkhi, const short* __restrict__ wklo,
    const short* __restrict__ wvhi, const short* __restrict__ wvlo,
    const float* __restrict__ kb, const float* __restrict__ vb,
    float* __restrict__ kout, short* __restrict__ vout)
{
    __shared__ char lds[65536];

    const int tid  = threadIdx.x;
    const int lane = tid & 63;
    const int wave = tid >> 6;
    const size_t boff = (size_t)blockIdx.y * ((size_t)CC * DHWC);
    const int sT = blockIdx.x * 128;
    const float* xb = img + boff + sT;
    const bf16x8* wkhf = (const bf16x8*)wkhi;
    const bf16x8* wklf = (const bf16x8*)wklo;
    const bf16x8* wvhf = (const bf16x8*)wvhi;
    const bf16x8* wvlf = (const bf16x8*)wvlo;

    f32x4 acck[8], accv[8];
    #pragma unroll
    for (int j = 0; j < 8; ++j) {
        acck[j] = (f32x4){0.f, 0.f, 0.f, 0.f};
        accv[j] = (f32x4){0.f, 0.f, 0.f, 0.f};
    }

    const int s_l = tid & 127;
    const int k8  = tid >> 7;

    float xr[8];
    #pragma unroll
    for (int r = 0; r < 8; ++r)
        xr[r] = xb[(size_t)(k8 * 8 + r) * DHWC + s_l];
    {
        bf16x8 hv, lv;
        #pragma unroll
        for (int r = 0; r < 8; ++r) {
            const short h = f2bf(xr[r]);
            hv[r] = h;
            lv[r] = f2bf(xr[r] - bf2f(h));
        }
        const int off = swz(s_l, k8 * 8);
        *(bf16x8*)(lds + off) = hv;
        *(bf16x8*)(lds + 16384 + off) = lv;
    }

    #pragma unroll
    for (int t = 0; t < 4; ++t) {
        if (t < 3) {
            #pragma unroll
            for (int r = 0; r < 8; ++r)
                xr[r] = xb[(size_t)((t + 1) * 64 + k8 * 8 + r) * DHWC + s_l];
        }
        __syncthreads();

        const char* bhib = lds + (t & 1) * 32768;
        const char* blob = bhib + 16384;
        #pragma unroll
        for (int kk = 0; kk < 2; ++kk) {
            const int idx = (wave * 8 + 2 * t + kk) * 64 + lane;
            const bf16x8 akh = wkhf[idx];
            const bf16x8 akl = wklf[idx];
            const bf16x8 avh = wvhf[idx];
            const bf16x8 avl = wvlf[idx];
            #pragma unroll
            for (int j = 0; j < 8; ++j) {
                const int s = j * 16 + (lane & 15);
                const int k = kk * 32 + (lane >> 4) * 8;
                const bf16x8 bh = *(const bf16x8*)(bhib + swz(s, k));
                const bf16x8 bl = *(const bf16x8*)(blob + swz(s, k));
                f32x4 c = acck[j];
                c = __builtin_amdgcn_mfma_f32_16x16x32_bf16(akh, bh, c, 0, 0, 0);
                c = __builtin_amdgcn_mfma_f32_16x16x32_bf16(akh, bl, c, 0, 0, 0);
                c = __builtin_amdgcn_mfma_f32_16x16x32_bf16(akl, bh, c, 0, 0, 0);
                acck[j] = c;
                f32x4 d = accv[j];
                d = __builtin_amdgcn_mfma_f32_16x16x32_bf16(avh, bh, d, 0, 0, 0);
                d = __builtin_amdgcn_mfma_f32_16x16x32_bf16(avh, bl, d, 0, 0, 0);
                d = __builtin_amdgcn_mfma_f32_16x16x32_bf16(avl, bh, d, 0, 0, 0);
                accv[j] = d;
            }
        }

        if (t < 3) {
            bf16x8 hv, lv;
            #pragma unroll
            for (int r = 0; r < 8; ++r) {
                const short h = f2bf(xr[r]);
                hv[r] = h;
                lv[r] = f2bf(xr[r] - bf2f(h));
            }
            const int off = ((t + 1) & 1) * 32768 + swz(s_l, k8 * 8);
            *(bf16x8*)(lds + off) = hv;
            *(bf16x8*)(lds + 16384 + off) = lv;
        }
    }

    float* ko = kout + boff + sT;
    short* vo = vout + boff + sT;
    const int n_l = lane & 15;
    const int m4  = (lane >> 4) * 4;
    #pragma unroll
    for (int r = 0; r < 4; ++r) {
        const int o = wave * 16 + m4 + r;
        const float kbv = kb[o];
        const float vbv = vb[o];
        #pragma unroll
        for (int j = 0; j < 8; ++j) {
            ko[(size_t)o * DHWC + j * 16 + n_l] = acck[j][r] + kbv;
            vo[(size_t)o * DHWC + j * 16 + n_l] = f2bf(accv[j][r] + vbv);
        }
    }
}

// ---------------------------------------------------------------------------
// attention (round-6 verbatim). One block (256 thr = 4 waves) per (b,c,d) slab.
// q,k fp32 (split at stage); v bf16 shorts. wv fp32 in-place over q buffer.
// ---------------------------------------------------------------------------
__global__ __launch_bounds__(256, 4) void attn_mfma_kernel(
    const float* q, const float* __restrict__ kg,
    const short* __restrict__ vsh, float* wv)
{
    __shared__ char lds[40960];
    const int QHI = 0, QLO = 8192, KHI = 16384, KLO = 24576, VT = 32768;

    const int tid  = threadIdx.x;
    const int lane = tid & 63;
    const int wsx  = tid >> 6;           // wave 0..3
    const size_t base = (size_t)blockIdx.x * 4096;

    {
        const int r  = tid >> 2;         // 0..63
        const int cb = (tid & 3) * 16;
        #pragma unroll
        for (int half = 0; half < 2; ++half) {
            const int c = cb + half * 8;
            const float4 qa = *(const float4*)(q  + base + r * 64 + c);
            const float4 qb = *(const float4*)(q  + base + r * 64 + c + 4);
            const float4 ka = *(const float4*)(kg + base + r * 64 + c);
            const float4 kb = *(const float4*)(kg + base + r * 64 + c + 4);
            bf16x8 qh, ql, kh, kl;
            #pragma unroll
            for (int e = 0; e < 4; ++e) {
                float xq = ((const float*)&qa)[e];
                short h = f2bf(xq); qh[e] = h; ql[e] = f2bf(xq - bf2f(h));
                xq = ((const float*)&qb)[e];
                h = f2bf(xq); qh[e + 4] = h; ql[e + 4] = f2bf(xq - bf2f(h));
                float xk = ((const float*)&ka)[e];
                h = f2bf(xk); kh[e] = h; kl[e] = f2bf(xk - bf2f(h));
                xk = ((const float*)&kb)[e];
                h = f2bf(xk); kh[e + 4] = h; kl[e + 4] = f2bf(xk - bf2f(h));
            }
            const int off = swz(r, c);
            *(bf16x8*)(lds + QHI + off) = qh;
            *(bf16x8*)(lds + QLO + off) = ql;
            *(bf16x8*)(lds + KHI + off) = kh;
            *(bf16x8*)(lds + KLO + off) = kl;
        }
        const short* vpl = vsh + base;
        const int x0 = (tid >> 4) * 4;
        const int w0 = (tid & 15) * 4;
        bf16x4 vr[4];
        #pragma unroll
        for (int i = 0; i < 4; ++i)
            vr[i] = *(const bf16x4*)(vpl + (x0 + i) * 64 + w0);
        #pragma unroll
        for (int j = 0; j < 4; ++j) {
            bf16x4 tv;
            #pragma unroll
            for (int i = 0; i < 4; ++i) tv[i] = vr[i][j];
            *(bf16x4*)(lds + VT + vswz(w0 + j, x0)) = tv;
        }
    }
    __syncthreads();

    f32x4 acc[4];
    #pragma unroll
    for (int j = 0; j < 4; ++j) acc[j] = (f32x4){0.f, 0.f, 0.f, 0.f};

    const int arow = wsx * 16 + (lane & 15);
    #pragma unroll
    for (int kk = 0; kk < 2; ++kk) {
        const int kcol = kk * 32 + (lane >> 4) * 8;
        const bf16x8 aqh = *(const bf16x8*)(lds + QHI + swz(arow, kcol));
        const bf16x8 aql = *(const bf16x8*)(lds + QLO + swz(arow, kcol));
        #pragma unroll
        for (int j = 0; j < 4; ++j) {
            const int brow = j * 16 + (lane & 15);
            const bf16x8 bkh = *(const bf16x8*)(lds + KHI + swz(brow, kcol));
            const bf16x8 bkl = *(const bf16x8*)(lds + KLO + swz(brow, kcol));
            f32x4 c = acc[j];
            c = __builtin_amdgcn_mfma_f32_16x16x32_bf16(aqh, bkh, c, 0, 0, 0);
            c = __builtin_amdgcn_mfma_f32_16x16x32_bf16(aqh, bkl, c, 0, 0, 0);
            c = __builtin_amdgcn_mfma_f32_16x16x32_bf16(aql, bkh, c, 0, 0, 0);
            acc[j] = c;
        }
    }

    float p[4][4], invs[4];
    #pragma unroll
    for (int r = 0; r < 4; ++r) {
        float m = fmaxf(fmaxf(acc[0][r], acc[1][r]), fmaxf(acc[2][r], acc[3][r]));
        m = fmaxf(m, __shfl_xor(m, 1));
        m = fmaxf(m, __shfl_xor(m, 2));
        m = fmaxf(m, __shfl_xor(m, 4));
        m = fmaxf(m, __shfl_xor(m, 8));
        float s = 0.f;
        #pragma unroll
        for (int j = 0; j < 4; ++j) { p[j][r] = __expf(acc[j][r] - m); s += p[j][r]; }
        s += __shfl_xor(s, 1);
        s += __shfl_xor(s, 2);
        s += __shfl_xor(s, 4);
        s += __shfl_xor(s, 8);
        invs[r] = 1.f / s;
    }

    __syncthreads();

    #pragma unroll
    for (int r = 0; r < 4; ++r) {
        const int row = wsx * 16 + (lane >> 4) * 4 + r;
        #pragma unroll
        for (int j = 0; j < 4; ++j) {
            const int col = j * 16 + (lane & 15);
            *(short*)(lds + QHI + swz(row, col)) = f2bf(p[j][r]);
        }
    }
    __syncthreads();

    f32x4 o_[4];
    #pragma unroll
    for (int j = 0; j < 4; ++j) o_[j] = (f32x4){0.f, 0.f, 0.f, 0.f};

    #pragma unroll
    for (int kk = 0; kk < 2; ++kk) {
        const int kcol = kk * 32 + (lane >> 4) * 8;
        const bf16x8 aph = *(const bf16x8*)(lds + QHI + swz(arow, kcol));
        #pragma unroll
        for (int j = 0; j < 4; ++j) {
            const int brow = j * 16 + (lane & 15);
            const bf16x8 bvh = *(const bf16x8*)(lds + VT + vswz(brow, kcol));
            o_[j] = __builtin_amdgcn_mfma_f32_16x16x32_bf16(aph, bvh, o_[j], 0, 0, 0);
        }
    }

    #pragma unroll
    for (int r = 0; r < 4; ++r) {
        const int h = wsx * 16 + (lane >> 4) * 4 + r;
        #pragma unroll
        for (int j = 0; j < 4; ++j)
            wv[base + (size_t)h * 64 + j * 16 + (lane & 15)] = o_[j][r] * invs[r];
    }
}

// ---------------------------------------------------------------------------
// fused tail, BN=128: out = relu(W2 * relu(W1 * wv + b1) + b2).
// Phase A: split-staged GEMM1 (like conv). Phase B: a = relu(...) hi-only bf16
// into [128 s][256 k] LDS (64 KB, reuses staging). Phase C: GEMM2, 2-MFMA.
// ---------------------------------------------------------------------------
__global__ __launch_bounds__(1024, 4) void tail_fused_kernel(
    const float* __restrict__ x,
    const short* __restrict__ w1hi, const short* __restrict__ w1lo,
    const float* __restrict__ b1,
    const short* __restrict__ w2hi, const short* __restrict__ w2lo,
    const float* __restrict__ b2,
    float* __restrict__ out)
{
    __shared__ char lds[65536];

    const int tid  = threadIdx.x;
    const int lane = tid & 63;
    const int wave = tid >> 6;
    const size_t boff = (size_t)blockIdx.y * ((size_t)CC * DHWC);
    const int sT = blockIdx.x * 128;
    const float* xb = x + boff + sT;
    const bf16x8* w1hf = (const bf16x8*)w1hi;
    const bf16x8* w1lf = (const bf16x8*)w1lo;

    f32x4 acc[8];
    #pragma unroll
    for (int j = 0; j < 8; ++j) acc[j] = (f32x4){0.f, 0.f, 0.f, 0.f};

    const int s_l = tid & 127;
    const int k8  = tid >> 7;

    float xr[8];
    #pragma unroll
    for (int r = 0; r < 8; ++r)
        xr[r] = xb[(size_t)(k8 * 8 + r) * DHWC + s_l];
    {
        bf16x8 hv, lv;
        #pragma unroll
        for (int r = 0; r < 8; ++r) {
            const short h = f2bf(xr[r]);
            hv[r] = h;
            lv[r] = f2bf(xr[r] - bf2f(h));
        }
        const int off = swz(s_l, k8 * 8);
        *(bf16x8*)(lds + off) = hv;
        *(bf16x8*)(lds + 16384 + off) = lv;
    }

    #pragma unroll
    for (int t = 0; t < 4; ++t) {
        if (t < 3) {
            #pragma unroll
            for (int r = 0; r < 8; ++r)
                xr[r] = xb[(size_t)((t + 1) * 64 + k8 * 8 + r) * DHWC + s_l];
        }
        __syncthreads();

        const char* bhib = lds + (t & 1) * 32768;
        const char* blob = bhib + 16384;
        #pragma unroll
        for (int kk = 0; kk < 2; ++kk) {
            const int idx = (wave * 8 + 2 * t + kk) * 64 + lane;
            const bf16x8 a1h = w1hf[idx];
            const bf16x8 a1l = w1lf[idx];
            #pragma unroll
            for (int j = 0; j < 8; ++j) {
                const int s = j * 16 + (lane & 15);
                const int k = kk * 32 + (lane >> 4) * 8;
                const bf16x8 bh = *(const bf16x8*)(bhib + swz(s, k));
                const bf16x8 bl = *(const bf16x8*)(blob + swz(s, k));
                f32x4 c = acc[j];
                c = __builtin_amdgcn_mfma_f32_16x16x32_bf16(a1h, bh, c, 0, 0, 0);
                c = __builtin_amdgcn_mfma_f32_16x16x32_bf16(a1h, bl, c, 0, 0, 0);
                c = __builtin_amdgcn_mfma_f32_16x16x32_bf16(a1l, bh, c, 0, 0, 0);
                acc[j] = c;
            }
        }

        if (t < 3) {
            bf16x8 hv, lv;
            #pragma unroll
            for (int r = 0; r < 8; ++r) {
                const short h = f2bf(xr[r]);
                hv[r] = h;
                lv[r] = f2bf(xr[r] - bf2f(h));
            }
            const int off = ((t + 1) & 1) * 32768 + swz(s_l, k8 * 8);
            *(bf16x8*)(lds + off) = hv;
            *(bf16x8*)(lds + 16384 + off) = lv;
        }
    }

    // ---- phase B: a = relu(acc + b1), hi-only bf16 into [128 s][256 k] ----
    __syncthreads();   // all phase-A LDS reads done
    {
        const int m4 = (lane >> 4) * 4;
        #pragma unroll
        for (int r = 0; r < 4; ++r) {
            const int o = wave * 16 + m4 + r;
            const float bv = b1[o];
            #pragma unroll
            for (int j = 0; j < 8; ++j) {
                const int s = j * 16 + (lane & 15);
                *(short*)(lds + swz512(s, o)) = f2bf(fmaxf(acc[j][r] + bv, 0.f));
            }
        }
    }
    __syncthreads();

    // ---- phase C: GEMM2 (a hi-only -> 2 MFMA per frag) ----
    f32x4 acc2[8];
    #pragma unroll
    for (int j = 0; j < 8; ++j) acc2[j] = (f32x4){0.f, 0.f, 0.f, 0.f};

    const bf16x8* w2hf = (const bf16x8*)w2hi;
    const bf16x8* w2lf = (const bf16x8*)w2lo;
    #pragma unroll
    for (int t2 = 0; t2 < 8; ++t2) {
        const int idx = (wave * 8 + t2) * 64 + lane;
        const bf16x8 a2h = w2hf[idx];
        const bf16x8 a2l = w2lf[idx];
        #pragma unroll
        for (int j = 0; j < 8; ++j) {
            const int s = j * 16 + (lane & 15);
            const int k = t2 * 32 + (lane >> 4) * 8;
            const bf16x8 bh = *(const bf16x8*)(lds + swz512(s, k));
            f32x4 c = acc2[j];
            c = __builtin_amdgcn_mfma_f32_16x16x32_bf16(a2h, bh, c, 0, 0, 0);
            c = __builtin_amdgcn_mfma_f32_16x16x32_bf16(a2l, bh, c, 0, 0, 0);
            acc2[j] = c;
        }
    }

    float* ob = out + boff + sT;
    const int n_l = lane & 15;
    const int m4  = (lane >> 4) * 4;
    #pragma unroll
    for (int r = 0; r < 4; ++r) {
        const int o = wave * 16 + m4 + r;
        const float bv = b2[o];
        #pragma unroll
        for (int j = 0; j < 8; ++j)
            ob[(size_t)o * DHWC + j * 16 + n_l] = fmaxf(acc2[j][r] + bv, 0.f);
    }
}

// ---------------------------------------------------------------------------
// Pipeline: prep_w -> q=conv(eeg) ; {k,v}=kv_conv(img) -> attn -> tail.
// ws: qbuf (N f32, becomes wv in-place) | kbuf (N f32) | weights.
// d_out: v (N shorts) during attn, then final fp32 output.
// ---------------------------------------------------------------------------
extern "C" void kernel_launch(void* const* d_in, const int* in_sizes, int n_in,
                              void* d_out, int out_size, void* d_ws, size_t ws_size,
                              hipStream_t stream)
{
    const float* eeg    = (const float*)d_in[0];
    const float* img    = (const float*)d_in[1];
    const float* q_w    = (const float*)d_in[2];
    const float* q_b    = (const float*)d_in[3];
    const float* k_w    = (const float*)d_in[4];
    const float* k_b    = (const float*)d_in[5];
    const float* v_w    = (const float*)d_in[6];
    const float* v_b    = (const float*)d_in[7];
    const float* attn_w = (const float*)d_in[8];
    const float* attn_b = (const float*)d_in[9];
    const float* out_w  = (const float*)d_in[10];
    const float* out_b  = (const float*)d_in[11];

    const size_t N = (size_t)NBC * CC * DHWC;
    float* qbuf = (float*)d_ws;
    float* kbuf = qbuf + N;
    short* wsp  = (short*)(kbuf + N);
    short* vsh  = (short*)d_out;
    float* outp = (float*)d_out;

    hipLaunchKernelGGL(prep_w_kernel, dim3(16, 8, 5), dim3(64), 0, stream,
                       q_w, k_w, v_w, attn_w, out_w, wsp);

    const dim3 cgrid(DHWC / 128, NBC);

    hipLaunchKernelGGL(conv_mfma_kernel, cgrid, dim3(1024), 0, stream,
                       eeg, wsp, wsp + 65536, q_b, qbuf, 0);

    hipLaunchKernelGGL(kv_conv_kernel, cgrid, dim3(1024), 0, stream,
                       img, wsp + 131072, wsp + 131072 + 65536,
                       wsp + 2 * 131072, wsp + 2 * 131072 + 65536,
                       k_b, v_b, kbuf, vsh);

    hipLaunchKernelGGL(attn_mfma_kernel, dim3(NBC * CC * 16), dim3(256), 0, stream,
                       qbuf, kbuf, vsh, qbuf);

    hipLaunchKernelGGL(tail_fused_kernel, cgrid, dim3(1024), 0, stream,
                       qbuf, wsp + 3 * 131072, wsp + 3 * 131072 + 65536, attn_b,
                       wsp + 4 * 131072, wsp + 4 * 131072 + 65536, out_b, outp);
}

// Round 8
// 392.578 us; speedup vs baseline: 1.3623x; 1.0447x over previous
//
#include <hip/hip_runtime.h>

#define CC   256
#define DHWC 65536          // D*H*W
#define NBC  2              // batch

typedef __attribute__((ext_vector_type(8))) short bf16x8;
typedef __attribute__((ext_vector_type(4))) short bf16x4;
typedef __attribute__((ext_vector_type(4))) float f32x4;

// ---- bf16 split helpers (branchless, bit-level, RTN-even) --------------------
__device__ __forceinline__ short f2bf(float x) {
    unsigned u = __builtin_bit_cast(unsigned, x);
    unsigned r = (u + 0x7fffu + ((u >> 16) & 1u)) >> 16;
    return (short)r;
}
__device__ __forceinline__ float bf2f(short h) {
    unsigned u = ((unsigned)(unsigned short)h) << 16;
    return __builtin_bit_cast(float, u);
}

// swizzled byte offset into a [R rows][64 c] bf16 LDS plane (row stride 128 B).
__device__ __forceinline__ int swz(int r, int c) {
    return (r * 128 + c * 2) ^ ((r & 7) << 4);
}
// richer swizzle for the V^T plane (write pattern is rows at stride 4)
__device__ __forceinline__ int vswz(int r, int c) {
    return (r * 128 + c * 2) ^ (((r ^ (r >> 3)) & 7) << 4);
}
// swizzled byte offset into a [128 s][256 k] bf16 LDS plane (row stride 512 B).
__device__ __forceinline__ int swz512(int s, int k) {
    return (s * 512 + k * 2) ^ ((s & 7) << 4);
}
// swizzled byte offset into a [256 rows][128 s] bf16 bounce plane (stride 256 B).
__device__ __forceinline__ int swz256(int r, int s) {
    return (r * 256 + s * 2) ^ ((r & 7) << 4);
}

// ---------------------------------------------------------------------------
// prep: split 5 weight matrices [256][256] fp32 into hi/lo bf16 planes stored
// fragment-major for mfma_f32_16x16x32_bf16 A-operand. Matrix m: hi at
// wsp + m*131072, lo at +65536.
// ---------------------------------------------------------------------------
__global__ void prep_w_kernel(const float* __restrict__ q_w, const float* __restrict__ k_w,
                              const float* __restrict__ v_w, const float* __restrict__ attn_w,
                              const float* __restrict__ out_w, short* __restrict__ wsp)
{
    const int l  = threadIdx.x;          // 64
    const int fo = blockIdx.x;           // 16
    const int t  = blockIdx.y;           // 8
    const int m  = blockIdx.z;           // 5
    const float* w = (m == 0) ? q_w : (m == 1) ? k_w : (m == 2) ? v_w
                   : (m == 3) ? attn_w : out_w;
    short* whi = wsp + (size_t)m * 131072;
    short* wlo = whi + 65536;

    const int o = fo * 16 + (l & 15);
    const int k = t * 32 + (l >> 4) * 8;

    bf16x8 hv, lv;
    #pragma unroll
    for (int r = 0; r < 8; ++r) {
        const float x = w[o * 256 + k + r];
        const short h = f2bf(x);
        hv[r] = h;
        lv[r] = f2bf(x - bf2f(h));
    }
    const int idx = (fo * 8 + t) * 64 + l;
    *(bf16x8*)(whi + idx * 8) = hv;
    *(bf16x8*)(wlo + idx * 8) = lv;
}

// ---------------------------------------------------------------------------
// conv1x1 (q), BN=128, 1024 thr = 16 waves (round-7 verbatim).
// ---------------------------------------------------------------------------
__global__ __launch_bounds__(1024, 4) void conv_mfma_kernel(
    const float* __restrict__ x, const short* __restrict__ whi,
    const short* __restrict__ wlo, const float* __restrict__ bias,
    float* __restrict__ out)
{
    __shared__ char lds[65536];

    const int tid  = threadIdx.x;
    const int lane = tid & 63;
    const int wave = tid >> 6;            // 0..15
    const size_t boff = (size_t)blockIdx.y * ((size_t)CC * DHWC);
    const int sT = blockIdx.x * 128;
    const float* xb = x + boff + sT;
    const bf16x8* whf = (const bf16x8*)whi;
    const bf16x8* wlf = (const bf16x8*)wlo;

    f32x4 acc[8];
    #pragma unroll
    for (int j = 0; j < 8; ++j) acc[j] = (f32x4){0.f, 0.f, 0.f, 0.f};

    const int s_l = tid & 127;
    const int k8  = tid >> 7;     // 0..7

    float xr[8];
    #pragma unroll
    for (int r = 0; r < 8; ++r)
        xr[r] = xb[(size_t)(k8 * 8 + r) * DHWC + s_l];
    {
        bf16x8 hv, lv;
        #pragma unroll
        for (int r = 0; r < 8; ++r) {
            const short h = f2bf(xr[r]);
            hv[r] = h;
            lv[r] = f2bf(xr[r] - bf2f(h));
        }
        const int off = swz(s_l, k8 * 8);
        *(bf16x8*)(lds + off) = hv;
        *(bf16x8*)(lds + 16384 + off) = lv;
    }

    #pragma unroll
    for (int t = 0; t < 4; ++t) {
        if (t < 3) {
            #pragma unroll
            for (int r = 0; r < 8; ++r)
                xr[r] = xb[(size_t)((t + 1) * 64 + k8 * 8 + r) * DHWC + s_l];
        }
        __syncthreads();

        const char* bhib = lds + (t & 1) * 32768;
        const char* blob = bhib + 16384;
        #pragma unroll
        for (int kk = 0; kk < 2; ++kk) {
            const int idx = (wave * 8 + 2 * t + kk) * 64 + lane;
            const bf16x8 a1h = whf[idx];
            const bf16x8 a1l = wlf[idx];
            #pragma unroll
            for (int j = 0; j < 8; ++j) {
                const int s = j * 16 + (lane & 15);
                const int k = kk * 32 + (lane >> 4) * 8;
                const bf16x8 bh = *(const bf16x8*)(bhib + swz(s, k));
                const bf16x8 bl = *(const bf16x8*)(blob + swz(s, k));
                f32x4 c = acc[j];
                c = __builtin_amdgcn_mfma_f32_16x16x32_bf16(a1h, bh, c, 0, 0, 0);
                c = __builtin_amdgcn_mfma_f32_16x16x32_bf16(a1h, bl, c, 0, 0, 0);
                c = __builtin_amdgcn_mfma_f32_16x16x32_bf16(a1l, bh, c, 0, 0, 0);
                acc[j] = c;
            }
        }

        if (t < 3) {
            bf16x8 hv, lv;
            #pragma unroll
            for (int r = 0; r < 8; ++r) {
                const short h = f2bf(xr[r]);
                hv[r] = h;
                lv[r] = f2bf(xr[r] - bf2f(h));
            }
            const int off = ((t + 1) & 1) * 32768 + swz(s_l, k8 * 8);
            *(bf16x8*)(lds + off) = hv;
            *(bf16x8*)(lds + 16384 + off) = lv;
        }
    }

    float* ob = out + boff + sT;
    const int n_l = lane & 15;
    const int m4  = (lane >> 4) * 4;
    #pragma unroll
    for (int r = 0; r < 4; ++r) {
        const int o = wave * 16 + m4 + r;
        const float bv = bias[o];
        #pragma unroll
        for (int j = 0; j < 8; ++j)
            ob[(size_t)o * DHWC + j * 16 + n_l] = acc[j][r] + bv;
    }
}

// ---------------------------------------------------------------------------
// kv conv, BN=128. k fp32 direct stores (64B quarters, no amp). v shorts go
// through an LDS bounce so each store instruction is 256B-contiguous.
// ---------------------------------------------------------------------------
__global__ __launch_bounds__(1024, 4) void kv_conv_kernel(
    const float* __restrict__ img,
    const short* __restrict__ wkhi, const short* __restrict__ wklo,
    const short* __restrict__ wvhi, const short* __restrict__ wvlo,
    const float* __restrict__ kb, const float* __restrict__ vb,
    float* __restrict__ kout, short* __restrict__ vout)
{
    __shared__ char lds[65536];

    const int tid  = threadIdx.x;
    const int lane = tid & 63;
    const int wave = tid >> 6;
    const size_t boff = (size_t)blockIdx.y * ((size_t)CC * DHWC);
    const int sT = blockIdx.x * 128;
    const float* xb = img + boff + sT;
    const bf16x8* wkhf = (const bf16x8*)wkhi;
    const bf16x8* wklf = (const bf16x8*)wklo;
    const bf16x8* wvhf = (const bf16x8*)wvhi;
    const bf16x8* wvlf = (const bf16x8*)wvlo;

    f32x4 acck[8], accv[8];
    #pragma unroll
    for (int j = 0; j < 8; ++j) {
        acck[j] = (f32x4){0.f, 0.f, 0.f, 0.f};
        accv[j] = (f32x4){0.f, 0.f, 0.f, 0.f};
    }

    const int s_l = tid & 127;
    const int k8  = tid >> 7;

    float xr[8];
    #pragma unroll
    for (int r = 0; r < 8; ++r)
        xr[r] = xb[(size_t)(k8 * 8 + r) * DHWC + s_l];
    {
        bf16x8 hv, lv;
        #pragma unroll
        for (int r = 0; r < 8; ++r) {
            const short h = f2bf(xr[r]);
            hv[r] = h;
            lv[r] = f2bf(xr[r] - bf2f(h));
        }
        const int off = swz(s_l, k8 * 8);
        *(bf16x8*)(lds + off) = hv;
        *(bf16x8*)(lds + 16384 + off) = lv;
    }

    #pragma unroll
    for (int t = 0; t < 4; ++t) {
        if (t < 3) {
            #pragma unroll
            for (int r = 0; r < 8; ++r)
                xr[r] = xb[(size_t)((t + 1) * 64 + k8 * 8 + r) * DHWC + s_l];
        }
        __syncthreads();

        const char* bhib = lds + (t & 1) * 32768;
        const char* blob = bhib + 16384;
        #pragma unroll
        for (int kk = 0; kk < 2; ++kk) {
            const int idx = (wave * 8 + 2 * t + kk) * 64 + lane;
            const bf16x8 akh = wkhf[idx];
            const bf16x8 akl = wklf[idx];
            const bf16x8 avh = wvhf[idx];
            const bf16x8 avl = wvlf[idx];
            #pragma unroll
            for (int j = 0; j < 8; ++j) {
                const int s = j * 16 + (lane & 15);
                const int k = kk * 32 + (lane >> 4) * 8;
                const bf16x8 bh = *(const bf16x8*)(bhib + swz(s, k));
                const bf16x8 bl = *(const bf16x8*)(blob + swz(s, k));
                f32x4 c = acck[j];
                c = __builtin_amdgcn_mfma_f32_16x16x32_bf16(akh, bh, c, 0, 0, 0);
                c = __builtin_amdgcn_mfma_f32_16x16x32_bf16(akh, bl, c, 0, 0, 0);
                c = __builtin_amdgcn_mfma_f32_16x16x32_bf16(akl, bh, c, 0, 0, 0);
                acck[j] = c;
                f32x4 d = accv[j];
                d = __builtin_amdgcn_mfma_f32_16x16x32_bf16(avh, bh, d, 0, 0, 0);
                d = __builtin_amdgcn_mfma_f32_16x16x32_bf16(avh, bl, d, 0, 0, 0);
                d = __builtin_amdgcn_mfma_f32_16x16x32_bf16(avl, bh, d, 0, 0, 0);
                accv[j] = d;
            }
        }

        if (t < 3) {
            bf16x8 hv, lv;
            #pragma unroll
            for (int r = 0; r < 8; ++r) {
                const short h = f2bf(xr[r]);
                hv[r] = h;
                lv[r] = f2bf(xr[r] - bf2f(h));
            }
            const int off = ((t + 1) & 1) * 32768 + swz(s_l, k8 * 8);
            *(bf16x8*)(lds + off) = hv;
            *(bf16x8*)(lds + 16384 + off) = lv;
        }
    }

    // ---- k epilogue: direct fp32 stores (64B quarters) ----
    float* ko = kout + boff + sT;
    const int n_l = lane & 15;
    const int m4  = (lane >> 4) * 4;
    #pragma unroll
    for (int r = 0; r < 4; ++r) {
        const int o = wave * 16 + m4 + r;
        const float kbv = kb[o];
        #pragma unroll
        for (int j = 0; j < 8; ++j)
            ko[(size_t)o * DHWC + j * 16 + n_l] = acck[j][r] + kbv;
    }

    // ---- v epilogue: LDS bounce -> 256B-contiguous stores ----
    __syncthreads();   // all waves done reading staging LDS
    #pragma unroll
    for (int r = 0; r < 4; ++r) {
        const int o = wave * 16 + m4 + r;
        const float vbv = vb[o];
        #pragma unroll
        for (int j = 0; j < 8; ++j)
            *(short*)(lds + swz256(o, j * 16 + n_l)) = f2bf(accv[j][r] + vbv);
    }
    __syncthreads();
    short* vo = vout + boff + sT;
    #pragma unroll
    for (int it = 0; it < 4; ++it) {
        const int row = it * 64 + wave * 4 + (lane >> 4);
        const int sc  = (lane & 15) * 8;        // 8 shorts = 16B
        const bf16x8 v8 = *(const bf16x8*)(lds + swz256(row, sc));
        *(bf16x8*)(vo + (size_t)row * DHWC + sc) = v8;
    }
}

// ---------------------------------------------------------------------------
// attention. One block (256 thr = 4 waves) per (b,c,d) slab.
// WVM=0: wv fp32 in-place over q buffer (round-7 path).
// WVM=1: wv bf16-hi into separate short buffer, via LDS bounce (coalesced).
// ---------------------------------------------------------------------------
template<int WVM>
__global__ __launch_bounds__(256, 4) void attn_mfma_kernel(
    const float* q, const float* __restrict__ kg,
    const short* __restrict__ vsh, float* wvf, short* __restrict__ wvs)
{
    __shared__ char lds[40960];
    const int QHI = 0, QLO = 8192, KHI = 16384, KLO = 24576, VT = 32768;

    const int tid  = threadIdx.x;
    const int lane = tid & 63;
    const int wsx  = tid >> 6;           // wave 0..3
    const size_t base = (size_t)blockIdx.x * 4096;

    {
        const int r  = tid >> 2;         // 0..63
        const int cb = (tid & 3) * 16;
        #pragma unroll
        for (int half = 0; half < 2; ++half) {
            const int c = cb + half * 8;
            const float4 qa = *(const float4*)(q  + base + r * 64 + c);
            const float4 qb = *(const float4*)(q  + base + r * 64 + c + 4);
            const float4 ka = *(const float4*)(kg + base + r * 64 + c);
            const float4 kb = *(const float4*)(kg + base + r * 64 + c + 4);
            bf16x8 qh, ql, kh, kl;
            #pragma unroll
            for (int e = 0; e < 4; ++e) {
                float xq = ((const float*)&qa)[e];
                short h = f2bf(xq); qh[e] = h; ql[e] = f2bf(xq - bf2f(h));
                xq = ((const float*)&qb)[e];
                h = f2bf(xq); qh[e + 4] = h; ql[e + 4] = f2bf(xq - bf2f(h));
                float xk = ((const float*)&ka)[e];
                h = f2bf(xk); kh[e] = h; kl[e] = f2bf(xk - bf2f(h));
                xk = ((const float*)&kb)[e];
                h = f2bf(xk); kh[e + 4] = h; kl[e + 4] = f2bf(xk - bf2f(h));
            }
            const int off = swz(r, c);
            *(bf16x8*)(lds + QHI + off) = qh;
            *(bf16x8*)(lds + QLO + off) = ql;
            *(bf16x8*)(lds + KHI + off) = kh;
            *(bf16x8*)(lds + KLO + off) = kl;
        }
        const short* vpl = vsh + base;
        const int x0 = (tid >> 4) * 4;
        const int w0 = (tid & 15) * 4;
        bf16x4 vr[4];
        #pragma unroll
        for (int i = 0; i < 4; ++i)
            vr[i] = *(const bf16x4*)(vpl + (x0 + i) * 64 + w0);
        #pragma unroll
        for (int j = 0; j < 4; ++j) {
            bf16x4 tv;
            #pragma unroll
            for (int i = 0; i < 4; ++i) tv[i] = vr[i][j];
            *(bf16x4*)(lds + VT + vswz(w0 + j, x0)) = tv;
        }
    }
    __syncthreads();

    f32x4 acc[4];
    #pragma unroll
    for (int j = 0; j < 4; ++j) acc[j] = (f32x4){0.f, 0.f, 0.f, 0.f};

    const int arow = wsx * 16 + (lane & 15);
    #pragma unroll
    for (int kk = 0; kk < 2; ++kk) {
        const int kcol = kk * 32 + (lane >> 4) * 8;
        const bf16x8 aqh = *(const bf16x8*)(lds + QHI + swz(arow, kcol));
        const bf16x8 aql = *(const bf16x8*)(lds + QLO + swz(arow, kcol));
        #pragma unroll
        for (int j = 0; j < 4; ++j) {
            const int brow = j * 16 + (lane & 15);
            const bf16x8 bkh = *(const bf16x8*)(lds + KHI + swz(brow, kcol));
            const bf16x8 bkl = *(const bf16x8*)(lds + KLO + swz(brow, kcol));
            f32x4 c = acc[j];
            c = __builtin_amdgcn_mfma_f32_16x16x32_bf16(aqh, bkh, c, 0, 0, 0);
            c = __builtin_amdgcn_mfma_f32_16x16x32_bf16(aqh, bkl, c, 0, 0, 0);
            c = __builtin_amdgcn_mfma_f32_16x16x32_bf16(aql, bkh, c, 0, 0, 0);
            acc[j] = c;
        }
    }

    float p[4][4], invs[4];
    #pragma unroll
    for (int r = 0; r < 4; ++r) {
        float m = fmaxf(fmaxf(acc[0][r], acc[1][r]), fmaxf(acc[2][r], acc[3][r]));
        m = fmaxf(m, __shfl_xor(m, 1));
        m = fmaxf(m, __shfl_xor(m, 2));
        m = fmaxf(m, __shfl_xor(m, 4));
        m = fmaxf(m, __shfl_xor(m, 8));
        float s = 0.f;
        #pragma unroll
        for (int j = 0; j < 4; ++j) { p[j][r] = __expf(acc[j][r] - m); s += p[j][r]; }
        s += __shfl_xor(s, 1);
        s += __shfl_xor(s, 2);
        s += __shfl_xor(s, 4);
        s += __shfl_xor(s, 8);
        invs[r] = 1.f / s;
    }

    __syncthreads();

    #pragma unroll
    for (int r = 0; r < 4; ++r) {
        const int row = wsx * 16 + (lane >> 4) * 4 + r;
        #pragma unroll
        for (int j = 0; j < 4; ++j) {
            const int col = j * 16 + (lane & 15);
            *(short*)(lds + QHI + swz(row, col)) = f2bf(p[j][r]);
        }
    }
    __syncthreads();

    f32x4 o_[4];
    #pragma unroll
    for (int j = 0; j < 4; ++j) o_[j] = (f32x4){0.f, 0.f, 0.f, 0.f};

    #pragma unroll
    for (int kk = 0; kk < 2; ++kk) {
        const int kcol = kk * 32 + (lane >> 4) * 8;
        const bf16x8 aph = *(const bf16x8*)(lds + QHI + swz(arow, kcol));
        #pragma unroll
        for (int j = 0; j < 4; ++j) {
            const int brow = j * 16 + (lane & 15);
            const bf16x8 bvh = *(const bf16x8*)(lds + VT + vswz(brow, kcol));
            o_[j] = __builtin_amdgcn_mfma_f32_16x16x32_bf16(aph, bvh, o_[j], 0, 0, 0);
        }
    }

    if (WVM == 0) {
        #pragma unroll
        for (int r = 0; r < 4; ++r) {
            const int h = wsx * 16 + (lane >> 4) * 4 + r;
            #pragma unroll
            for (int j = 0; j < 4; ++j)
                wvf[base + (size_t)h * 64 + j * 16 + (lane & 15)] = o_[j][r] * invs[r];
        }
    } else {
        // bounce via QHI plane (dead after PV + barrier), then coalesced out
        __syncthreads();
        #pragma unroll
        for (int r = 0; r < 4; ++r) {
            const int h = wsx * 16 + (lane >> 4) * 4 + r;
            #pragma unroll
            for (int j = 0; j < 4; ++j)
                *(short*)(lds + QHI + swz(h, j * 16 + (lane & 15))) = f2bf(o_[j][r] * invs[r]);
        }
        __syncthreads();
        #pragma unroll
        for (int it = 0; it < 4; ++it) {
            const int row = it * 16 + (tid >> 4);
            const int sc  = (tid & 15) * 4;     // 4 shorts = 8B
            bf16x4 v4;
            v4 = *(const bf16x4*)(lds + QHI + ((row * 128 + sc * 2) ^ ((row & 7) << 4)));
            *(bf16x4*)(wvs + base + (size_t)row * 64 + sc) = v4;
        }
    }
}

// ---------------------------------------------------------------------------
// fused tail: out = relu(W2 * relu(W1 * wv + b1) + b2).
// IM=0: wv fp32 (split-staged, 3-MFMA GEMM1). IM=1: wv bf16 shorts (hi-only
// staging, 2-MFMA GEMM1, half the fetch).
// ---------------------------------------------------------------------------
template<int IM>
__global__ __launch_bounds__(1024, 4) void tail_fused_kernel(
    const float* __restrict__ xf, const short* __restrict__ xs,
    const short* __restrict__ w1hi, const short* __restrict__ w1lo,
    const float* __restrict__ b1,
    const short* __restrict__ w2hi, const short* __restrict__ w2lo,
    const float* __restrict__ b2,
    float* __restrict__ out)
{
    __shared__ char lds[65536];

    const int tid  = threadIdx.x;
    const int lane = tid & 63;
    const int wave = tid >> 6;
    const size_t boff = (size_t)blockIdx.y * ((size_t)CC * DHWC);
    const int sT = blockIdx.x * 128;
    const bf16x8* w1hf = (const bf16x8*)w1hi;
    const bf16x8* w1lf = (const bf16x8*)w1lo;

    f32x4 acc[8];
    #pragma unroll
    for (int j = 0; j < 8; ++j) acc[j] = (f32x4){0.f, 0.f, 0.f, 0.f};

    const int s_l = tid & 127;
    const int k8  = tid >> 7;
    const float* xbf = xf + boff + sT;
    const short* xbs = xs + boff + sT;

    // per-buffer offsets: IM=0 -> hi/lo dbuf at {0,16384}+{32768}; IM=1 -> hi dbuf {0,16384}
    float xr[8];
    short sr[8];
    if (IM == 0) {
        #pragma unroll
        for (int r = 0; r < 8; ++r)
            xr[r] = xbf[(size_t)(k8 * 8 + r) * DHWC + s_l];
        bf16x8 hv, lv;
        #pragma unroll
        for (int r = 0; r < 8; ++r) {
            const short h = f2bf(xr[r]);
            hv[r] = h;
            lv[r] = f2bf(xr[r] - bf2f(h));
        }
        const int off = swz(s_l, k8 * 8);
        *(bf16x8*)(lds + off) = hv;
        *(bf16x8*)(lds + 16384 + off) = lv;
    } else {
        #pragma unroll
        for (int r = 0; r < 8; ++r)
            sr[r] = xbs[(size_t)(k8 * 8 + r) * DHWC + s_l];
        bf16x8 hv;
        #pragma unroll
        for (int r = 0; r < 8; ++r) hv[r] = sr[r];
        *(bf16x8*)(lds + swz(s_l, k8 * 8)) = hv;
    }

    #pragma unroll
    for (int t = 0; t < 4; ++t) {
        if (t < 3) {
            if (IM == 0) {
                #pragma unroll
                for (int r = 0; r < 8; ++r)
                    xr[r] = xbf[(size_t)((t + 1) * 64 + k8 * 8 + r) * DHWC + s_l];
            } else {
                #pragma unroll
                for (int r = 0; r < 8; ++r)
                    sr[r] = xbs[(size_t)((t + 1) * 64 + k8 * 8 + r) * DHWC + s_l];
            }
        }
        __syncthreads();

        const char* bhib = lds + (t & 1) * (IM == 0 ? 32768 : 16384);
        const char* blob = bhib + 16384;   // only used when IM==0
        #pragma unroll
        for (int kk = 0; kk < 2; ++kk) {
            const int idx = (wave * 8 + 2 * t + kk) * 64 + lane;
            const bf16x8 a1h = w1hf[idx];
            const bf16x8 a1l = w1lf[idx];
            #pragma unroll
            for (int j = 0; j < 8; ++j) {
                const int s = j * 16 + (lane & 15);
                const int k = kk * 32 + (lane >> 4) * 8;
                const bf16x8 bh = *(const bf16x8*)(bhib + swz(s, k));
                f32x4 c = acc[j];
                c = __builtin_amdgcn_mfma_f32_16x16x32_bf16(a1h, bh, c, 0, 0, 0);
                c = __builtin_amdgcn_mfma_f32_16x16x32_bf16(a1l, bh, c, 0, 0, 0);
                if (IM == 0) {
                    const bf16x8 bl = *(const bf16x8*)(blob + swz(s, k));
                    c = __builtin_amdgcn_mfma_f32_16x16x32_bf16(a1h, bl, c, 0, 0, 0);
                }
                acc[j] = c;
            }
        }

        if (t < 3) {
            const int off = ((t + 1) & 1) * (IM == 0 ? 32768 : 16384) + swz(s_l, k8 * 8);
            if (IM == 0) {
                bf16x8 hv, lv;
                #pragma unroll
                for (int r = 0; r < 8; ++r) {
                    const short h = f2bf(xr[r]);
                    hv[r] = h;
                    lv[r] = f2bf(xr[r] - bf2f(h));
                }
                *(bf16x8*)(lds + off) = hv;
                *(bf16x8*)(lds + 16384 + off) = lv;
            } else {
                bf16x8 hv;
                #pragma unroll
                for (int r = 0; r < 8; ++r) hv[r] = sr[r];
                *(bf16x8*)(lds + off) = hv;
            }
        }
    }

    // ---- phase B: a = relu(acc + b1), hi-only bf16 into [128 s][256 k] ----
    __syncthreads();
    {
        const int m4 = (lane >> 4) * 4;
        #pragma unroll
        for (int r = 0; r < 4; ++r) {
            const int o = wave * 16 + m4 + r;
            const float bv = b1[o];
            #pragma unroll
            for (int j = 0; j < 8; ++j) {
                const int s = j * 16 + (lane & 15);
                *(short*)(lds + swz512(s, o)) = f2bf(fmaxf(acc[j][r] + bv, 0.f));
            }
        }
    }
    __syncthreads();

    // ---- phase C: GEMM2 (a hi-only -> 2 MFMA per frag) ----
    f32x4 acc2[8];
    #pragma unroll
    for (int j = 0; j < 8; ++j) acc2[j] = (f32x4){0.f, 0.f, 0.f, 0.f};

    const bf16x8* w2hf = (const bf16x8*)w2hi;
    const bf16x8* w2lf = (const bf16x8*)w2lo;
    #pragma unroll
    for (int t2 = 0; t2 < 8; ++t2) {
        const int idx = (wave * 8 + t2) * 64 + lane;
        const bf16x8 a2h = w2hf[idx];
        const bf16x8 a2l = w2lf[idx];
        #pragma unroll
        for (int j = 0; j < 8; ++j) {
            const int s = j * 16 + (lane & 15);
            const int k = t2 * 32 + (lane >> 4) * 8;
            const bf16x8 bh = *(const bf16x8*)(lds + swz512(s, k));
            f32x4 c = acc2[j];
            c = __builtin_amdgcn_mfma_f32_16x16x32_bf16(a2h, bh, c, 0, 0, 0);
            c = __builtin_amdgcn_mfma_f32_16x16x32_bf16(a2l, bh, c, 0, 0, 0);
            acc2[j] = c;
        }
    }

    float* ob = out + boff + sT;
    const int n_l = lane & 15;
    const int m4  = (lane >> 4) * 4;
    #pragma unroll
    for (int r = 0; r < 4; ++r) {
        const int o = wave * 16 + m4 + r;
        const float bv = b2[o];
        #pragma unroll
        for (int j = 0; j < 8; ++j)
            ob[(size_t)o * DHWC + j * 16 + n_l] = fmaxf(acc2[j][r] + bv, 0.f);
    }
}

// ---------------------------------------------------------------------------
// Pipeline: prep_w -> q=conv(eeg) ; {k,v}=kv_conv(img) -> attn -> tail.
// Rich layout (if ws allows): qbuf 4N | kbuf 4N | wv shorts 2N | weights.
// Fallback: qbuf 4N (wv fp32 in-place) | kbuf 4N | weights.
// d_out: v (N shorts) during attn, then final fp32 output.
// ---------------------------------------------------------------------------
extern "C" void kernel_launch(void* const* d_in, const int* in_sizes, int n_in,
                              void* d_out, int out_size, void* d_ws, size_t ws_size,
                              hipStream_t stream)
{
    const float* eeg    = (const float*)d_in[0];
    const float* img    = (const float*)d_in[1];
    const float* q_w    = (const float*)d_in[2];
    const float* q_b    = (const float*)d_in[3];
    const float* k_w    = (const float*)d_in[4];
    const float* k_b    = (const float*)d_in[5];
    const float* v_w    = (const float*)d_in[6];
    const float* v_b    = (const float*)d_in[7];
    const float* attn_w = (const float*)d_in[8];
    const float* attn_b = (const float*)d_in[9];
    const float* out_w  = (const float*)d_in[10];
    const float* out_b  = (const float*)d_in[11];

    const size_t N = (size_t)NBC * CC * DHWC;
    float* qbuf = (float*)d_ws;
    float* kbuf = qbuf + N;
    const size_t need_rich = 4 * N + 4 * N + 2 * N + (size_t)5 * 131072 * 2;
    const bool rich = (ws_size >= need_rich);
    short* wvs = rich ? (short*)(kbuf + N) : (short*)nullptr;
    short* wsp = rich ? (wvs + N) : (short*)(kbuf + N);
    short* vsh  = (short*)d_out;
    float* outp = (float*)d_out;

    prep_w_kernel<<<dim3(16, 8, 5), dim3(64), 0, stream>>>(
        q_w, k_w, v_w, attn_w, out_w, wsp);

    const dim3 cgrid(DHWC / 128, NBC);

    conv_mfma_kernel<<<cgrid, dim3(1024), 0, stream>>>(
        eeg, wsp, wsp + 65536, q_b, qbuf);

    kv_conv_kernel<<<cgrid, dim3(1024), 0, stream>>>(
        img, wsp + 131072, wsp + 131072 + 65536,
        wsp + 2 * 131072, wsp + 2 * 131072 + 65536,
        k_b, v_b, kbuf, vsh);

    if (rich) {
        attn_mfma_kernel<1><<<dim3(NBC * CC * 16), dim3(256), 0, stream>>>(
            qbuf, kbuf, vsh, (float*)nullptr, wvs);
        tail_fused_kernel<1><<<cgrid, dim3(1024), 0, stream>>>(
            (const float*)nullptr, wvs,
            wsp + 3 * 131072, wsp + 3 * 131072 + 65536, attn_b,
            wsp + 4 * 131072, wsp + 4 * 131072 + 65536, out_b, outp);
    } else {
        attn_mfma_kernel<0><<<dim3(NBC * CC * 16), dim3(256), 0, stream>>>(
            qbuf, kbuf, vsh, qbuf, (short*)nullptr);
        tail_fused_kernel<0><<<cgrid, dim3(1024), 0, stream>>>(
            qbuf, (const short*)nullptr,
            wsp + 3 * 131072, wsp + 3 * 131072 + 65536, attn_b,
            wsp + 4 * 131072, wsp + 4 * 131072 + 65536, out_b, outp);
    }
}